// Round 1
// baseline (2114.364 us; speedup 1.0000x reference)
//
#include <hip/hip_runtime.h>

constexpr int N_U  = 100000;
constexpr int N_I  = 100000;
constexpr int NTOT = 200000;   // N_U + N_I
constexpr int D    = 64;
constexpr int Q    = 128;
constexpr int NNZ  = 3200000;
constexpr int SEG  = N_U * D;  // 6,400,000 floats per output segment

// ---------------- CSR build ----------------
__global__ void k_hist(const int* __restrict__ row, int* __restrict__ cnt) {
  int e = blockIdx.x * 256 + threadIdx.x;
  if (e < NNZ) atomicAdd(&cnt[row[e]], 1);
}

// 2048 elements per block, 256 threads x 8 items. Writes block-local exclusive
// scan into rowptr[i], block total into bsum[blk].
__global__ void k_scanA(const int* __restrict__ cnt, int* __restrict__ rowptr,
                        int* __restrict__ bsum) {
  __shared__ int s[256];
  const int t = threadIdx.x;
  const int base = blockIdx.x * 2048 + t * 8;
  int v[8];
  int sum = 0;
#pragma unroll
  for (int i = 0; i < 8; ++i) {
    int idx = base + i;
    int c = (idx < NTOT) ? cnt[idx] : 0;
    v[i] = sum;
    sum += c;
  }
  s[t] = sum;
  __syncthreads();
  const int own = sum;
  for (int off = 1; off < 256; off <<= 1) {
    int y = (t >= off) ? s[t - off] : 0;
    __syncthreads();
    s[t] += y;
    __syncthreads();
  }
  int excl = s[t] - own;  // exclusive prefix of this thread within block
  if (t == 255) bsum[blockIdx.x] = s[255];
#pragma unroll
  for (int i = 0; i < 8; ++i) {
    int idx = base + i;
    if (idx < NTOT) rowptr[idx] = excl + v[i];
  }
}

__global__ void k_scanB(int* __restrict__ bsum, int nblk) {
  __shared__ int s[128];
  const int t = threadIdx.x;
  int v = (t < nblk) ? bsum[t] : 0;
  s[t] = v;
  __syncthreads();
  for (int off = 1; off < 128; off <<= 1) {
    int y = (t >= off) ? s[t - off] : 0;
    __syncthreads();
    s[t] += y;
    __syncthreads();
  }
  if (t < nblk) bsum[t] = s[t] - v;  // exclusive block offsets
}

__global__ void k_scanC(const int* __restrict__ bsum, int* __restrict__ rowptr,
                        int* __restrict__ fill) {
  int i = blockIdx.x * 256 + threadIdx.x;
  if (i < NTOT) {
    int v = rowptr[i] + bsum[i >> 11];
    rowptr[i] = v;
    fill[i] = v;
  } else if (i == NTOT) {
    rowptr[NTOT] = NNZ;
  }
}

__global__ void k_scatter(const int* __restrict__ row, const int* __restrict__ col,
                          const float* __restrict__ val, int* __restrict__ fill,
                          int* __restrict__ colS, float* __restrict__ valS) {
  int e = blockIdx.x * 256 + threadIdx.x;
  if (e < NNZ) {
    int r = row[e];
    int p = atomicAdd(&fill[r], 1);
    colS[p] = col[e];
    valS[p] = val[e];
  }
}

// ---------------- SpMM (gather, wave per row, lane = d) ----------------
__global__ void k_spmm(const int* __restrict__ rowptr, const int* __restrict__ cols,
                       const float* __restrict__ vals, const float* __restrict__ xlo,
                       const float* __restrict__ xhi, float* __restrict__ y,
                       float* __restrict__ accu, float* __restrict__ acci) {
  const int r = (blockIdx.x * 256 + threadIdx.x) >> 6;
  const int lane = threadIdx.x & 63;
  if (r >= NTOT) return;
  const int e0 = rowptr[r], e1 = rowptr[r + 1];
  float sum = 0.f;
  for (int e = e0; e < e1; ++e) {
    int c = cols[e];
    float v = vals[e];
    const float* src = (c < N_U) ? (xlo + (size_t)c * D) : (xhi + (size_t)(c - N_U) * D);
    sum = fmaf(v, src[lane], sum);
  }
  y[(size_t)r * D + lane] = sum;
  if (r < N_U) accu[(size_t)r * D + lane] += sum;
  else         acci[(size_t)(r - N_U) * D + lane] += sum;
}

// ---------------- G1: P = W(Q x N) @ X(N x D), partial sums + atomic combine ----
__global__ void k_g1(const float* __restrict__ ut, const float* __restrict__ vt,
                     const float* __restrict__ accu, const float* __restrict__ acci,
                     float* __restrict__ P) {
  const float* W = blockIdx.y ? vt : ut;     // (Q, N_U) row-major
  const float* X = blockIdx.y ? acci : accu; // (N_U, D)
  float* out = P + (size_t)blockIdx.y * (Q * D);
  const int t = threadIdx.x;
  const int d = t & 63;
  const int qg = t >> 6;                     // 4 q-groups of 32
  const int n0 = blockIdx.x * 256;
  const int n1 = min(n0 + 256, N_U);
  float acc[32];
#pragma unroll
  for (int i = 0; i < 32; ++i) acc[i] = 0.f;
  for (int n = n0; n < n1; n += 4) {
    float x0 = X[(size_t)(n + 0) * D + d];
    float x1 = X[(size_t)(n + 1) * D + d];
    float x2 = X[(size_t)(n + 2) * D + d];
    float x3 = X[(size_t)(n + 3) * D + d];
#pragma unroll
    for (int i = 0; i < 32; ++i) {
      const int q = qg * 32 + i;
      float4 w = *reinterpret_cast<const float4*>(W + (size_t)q * N_U + n);
      acc[i] = fmaf(w.x, x0, acc[i]);
      acc[i] = fmaf(w.y, x1, acc[i]);
      acc[i] = fmaf(w.z, x2, acc[i]);
      acc[i] = fmaf(w.w, x3, acc[i]);
    }
  }
#pragma unroll
  for (int i = 0; i < 32; ++i) atomicAdd(&out[(qg * 32 + i) * D + d], acc[i]);
}

// ---------------- G2: out(N x D) = M(N x Q) @ P(Q x D), P column in registers --
__global__ void __launch_bounds__(256) k_g2(const float* __restrict__ M,
                                            const float* __restrict__ Pg,
                                            float* __restrict__ out) {
  const int d = threadIdx.x & 63;
  float p[Q];
#pragma unroll
  for (int q = 0; q < Q; ++q) p[q] = Pg[q * D + d];
  const int w = (blockIdx.x * 256 + threadIdx.x) >> 6;
  const int nw = (gridDim.x * 256) >> 6;
  for (int r = w; r < N_U; r += nw) {
    const float4* mrow = reinterpret_cast<const float4*>(M + (size_t)r * Q);
    float sum = 0.f;
#pragma unroll
    for (int q4 = 0; q4 < 32; ++q4) {
      float4 m = mrow[q4];
      sum = fmaf(m.x, p[4 * q4 + 0], sum);
      sum = fmaf(m.y, p[4 * q4 + 1], sum);
      sum = fmaf(m.z, p[4 * q4 + 2], sum);
      sum = fmaf(m.w, p[4 * q4 + 3], sum);
    }
    out[(size_t)r * D + d] = sum;
  }
}

__global__ void k_scale(float* __restrict__ p, int n4) {
  int i = blockIdx.x * 256 + threadIdx.x;
  if (i < n4) {
    float4 v = reinterpret_cast<float4*>(p)[i];
    v.x *= (1.f / 3.f);
    v.y *= (1.f / 3.f);
    v.z *= (1.f / 3.f);
    v.w *= (1.f / 3.f);
    reinterpret_cast<float4*>(p)[i] = v;
  }
}

extern "C" void kernel_launch(void* const* d_in, const int* in_sizes, int n_in,
                              void* d_out, int out_size, void* d_ws, size_t ws_size,
                              hipStream_t stream) {
  const float* user_emb = (const float*)d_in[0];
  const float* item_emb = (const float*)d_in[1];
  const int*   adj_row  = (const int*)d_in[2];
  const int*   adj_col  = (const int*)d_in[3];
  const float* adj_vals = (const float*)d_in[4];
  const float* ut       = (const float*)d_in[5];
  const float* vt       = (const float*)d_in[6];
  const float* u_mul_s  = (const float*)d_in[7];
  const float* v_mul_s  = (const float*)d_in[8];
  float* out = (float*)d_out;

  char* ws = (char*)d_ws;
  size_t off = 0;
  auto alloc = [&](size_t bytes) -> void* {
    void* p = ws + off;
    off = (off + bytes + 255) & ~(size_t)255;
    return p;
  };
  float* x      = (float*)alloc((size_t)NTOT * D * 4);   // 51.2 MB
  float* y      = (float*)alloc((size_t)NTOT * D * 4);   // 51.2 MB
  int*   colS   = (int*)alloc((size_t)NNZ * 4);          // 12.8 MB
  float* valS   = (float*)alloc((size_t)NNZ * 4);        // 12.8 MB
  int*   rowptr = (int*)alloc((size_t)(NTOT + 1) * 4);
  int*   fill   = (int*)alloc((size_t)NTOT * 4);
  int*   cnt    = (int*)alloc((size_t)NTOT * 4);
  int*   bsum   = (int*)alloc(1024);
  float* P      = (float*)alloc(2 * Q * D * 4);          // P[0]=ut@acc_u, P[1]=vt@acc_i

  float* acc_u = out;                    // seg0 -> mean_u after scale
  float* svd_u = out + (size_t)SEG;      // seg1
  float* acc_i = out + 2 * (size_t)SEG;  // seg2 -> mean_i after scale
  float* svd_i = out + 3 * (size_t)SEG;  // seg3

  hipMemsetAsync(cnt, 0, (size_t)NTOT * 4, stream);
  hipMemsetAsync(P, 0, 2 * Q * D * 4, stream);
  hipMemsetAsync(acc_u, 0, (size_t)SEG * 4, stream);
  hipMemsetAsync(acc_i, 0, (size_t)SEG * 4, stream);

  k_hist<<<(NNZ + 255) / 256, 256, 0, stream>>>(adj_row, cnt);
  k_scanA<<<98, 256, 0, stream>>>(cnt, rowptr, bsum);
  k_scanB<<<1, 128, 0, stream>>>(bsum, 98);
  k_scanC<<<(NTOT + 256) / 256, 256, 0, stream>>>(bsum, rowptr, fill);
  k_scatter<<<(NNZ + 255) / 256, 256, 0, stream>>>(adj_row, adj_col, adj_vals, fill,
                                                   colS, valS);

  // layer 1: gather from the (virtually concatenated) input embeddings
  k_spmm<<<(NTOT * 64) / 256, 256, 0, stream>>>(rowptr, colS, valS, user_emb, item_emb,
                                                x, acc_u, acc_i);
  // layer 2: x -> y
  k_spmm<<<(NTOT * 64) / 256, 256, 0, stream>>>(rowptr, colS, valS, x, x + (size_t)N_U * D,
                                                y, acc_u, acc_i);
  // layer 3: y -> x
  k_spmm<<<(NTOT * 64) / 256, 256, 0, stream>>>(rowptr, colS, valS, y, y + (size_t)N_U * D,
                                                x, acc_u, acc_i);

  // P_u = ut @ acc_u  (blockIdx.y = 0), P_v = vt @ acc_i (blockIdx.y = 1)
  k_g1<<<dim3(391, 2), 256, 0, stream>>>(ut, vt, acc_u, acc_i, P);

  // svd_u = u_mul_s @ P_v ; svd_i = v_mul_s @ P_u
  k_g2<<<2048, 256, 0, stream>>>(u_mul_s, P + Q * D, svd_u);
  k_g2<<<2048, 256, 0, stream>>>(v_mul_s, P, svd_i);

  // mean = acc / 3 (in place on seg0/seg2)
  k_scale<<<(SEG / 4 + 255) / 256, 256, 0, stream>>>(acc_u, SEG / 4);
  k_scale<<<(SEG / 4 + 255) / 256, 256, 0, stream>>>(acc_i, SEG / 4);
}

// Round 2
// 1618.229 us; speedup vs baseline: 1.3066x; 1.3066x over previous
//
#include <hip/hip_runtime.h>

constexpr int N_U  = 100000;
constexpr int N_I  = 100000;
constexpr int NTOT = 200000;   // N_U + N_I
constexpr int D    = 64;
constexpr int Q    = 128;
constexpr int NNZ  = 3200000;
constexpr int SEG  = N_U * D;  // 6,400,000 floats per output segment

// ---------------- CSR build ----------------
__global__ void k_hist(const int* __restrict__ row, int* __restrict__ cnt) {
  int e = blockIdx.x * 256 + threadIdx.x;
  if (e < NNZ) atomicAdd(&cnt[row[e]], 1);
}

// 2048 elements per block, 256 threads x 8 items. Writes block-local exclusive
// scan into rowptr[i], block total into bsum[blk].
__global__ void k_scanA(const int* __restrict__ cnt, int* __restrict__ rowptr,
                        int* __restrict__ bsum) {
  __shared__ int s[256];
  const int t = threadIdx.x;
  const int base = blockIdx.x * 2048 + t * 8;
  int v[8];
  int sum = 0;
#pragma unroll
  for (int i = 0; i < 8; ++i) {
    int idx = base + i;
    int c = (idx < NTOT) ? cnt[idx] : 0;
    v[i] = sum;
    sum += c;
  }
  s[t] = sum;
  __syncthreads();
  const int own = sum;
  for (int off = 1; off < 256; off <<= 1) {
    int y = (t >= off) ? s[t - off] : 0;
    __syncthreads();
    s[t] += y;
    __syncthreads();
  }
  int excl = s[t] - own;  // exclusive prefix of this thread within block
  if (t == 255) bsum[blockIdx.x] = s[255];
#pragma unroll
  for (int i = 0; i < 8; ++i) {
    int idx = base + i;
    if (idx < NTOT) rowptr[idx] = excl + v[i];
  }
}

__global__ void k_scanB(int* __restrict__ bsum, int nblk) {
  __shared__ int s[128];
  const int t = threadIdx.x;
  int v = (t < nblk) ? bsum[t] : 0;
  s[t] = v;
  __syncthreads();
  for (int off = 1; off < 128; off <<= 1) {
    int y = (t >= off) ? s[t - off] : 0;
    __syncthreads();
    s[t] += y;
    __syncthreads();
  }
  if (t < nblk) bsum[t] = s[t] - v;  // exclusive block offsets
}

__global__ void k_scanC(const int* __restrict__ bsum, int* __restrict__ rowptr,
                        int* __restrict__ fill) {
  int i = blockIdx.x * 256 + threadIdx.x;
  if (i < NTOT) {
    int v = rowptr[i] + bsum[i >> 11];
    rowptr[i] = v;
    fill[i] = v;
  } else if (i == NTOT) {
    rowptr[NTOT] = NNZ;
  }
}

__global__ void k_scatter(const int* __restrict__ row, const int* __restrict__ col,
                          const float* __restrict__ val, int* __restrict__ fill,
                          int2* __restrict__ edges) {
  int e = blockIdx.x * 256 + threadIdx.x;
  if (e < NNZ) {
    int r = row[e];
    int p = atomicAdd(&fill[r], 1);
    edges[p] = make_int2(col[e], __float_as_int(val[e]));
  }
}

// ---------------- SpMM (gather, wave per row, lane = d, 8-deep MLP) ---------
// MODE 0: y = sum, acc = sum           (layer 1, initializes acc)
// MODE 1: y = sum, acc += sum          (layer 2)
// MODE 2: no y,    acc = (acc+sum)/3   (layer 3, fused mean)
template <int MODE>
__global__ void k_spmm(const int* __restrict__ rowptr, const int2* __restrict__ edges,
                       const float* __restrict__ xin, float* __restrict__ y,
                       float* __restrict__ accu, float* __restrict__ acci) {
  const int r = (blockIdx.x * 256 + threadIdx.x) >> 6;
  const int lane = threadIdx.x & 63;
  if (r >= NTOT) return;
  const int e0 = rowptr[r], e1 = rowptr[r + 1];
  float sum = 0.f;
  int e = e0;
  for (; e + 8 <= e1; e += 8) {
    int2 d0 = edges[e + 0], d1 = edges[e + 1], d2 = edges[e + 2], d3 = edges[e + 3];
    int2 d4 = edges[e + 4], d5 = edges[e + 5], d6 = edges[e + 6], d7 = edges[e + 7];
    float a0 = xin[((size_t)d0.x << 6) + lane];
    float a1 = xin[((size_t)d1.x << 6) + lane];
    float a2 = xin[((size_t)d2.x << 6) + lane];
    float a3 = xin[((size_t)d3.x << 6) + lane];
    float a4 = xin[((size_t)d4.x << 6) + lane];
    float a5 = xin[((size_t)d5.x << 6) + lane];
    float a6 = xin[((size_t)d6.x << 6) + lane];
    float a7 = xin[((size_t)d7.x << 6) + lane];
    sum = fmaf(__int_as_float(d0.y), a0, sum);
    sum = fmaf(__int_as_float(d1.y), a1, sum);
    sum = fmaf(__int_as_float(d2.y), a2, sum);
    sum = fmaf(__int_as_float(d3.y), a3, sum);
    sum = fmaf(__int_as_float(d4.y), a4, sum);
    sum = fmaf(__int_as_float(d5.y), a5, sum);
    sum = fmaf(__int_as_float(d6.y), a6, sum);
    sum = fmaf(__int_as_float(d7.y), a7, sum);
  }
  for (; e + 2 <= e1; e += 2) {
    int2 d0 = edges[e + 0], d1 = edges[e + 1];
    float a0 = xin[((size_t)d0.x << 6) + lane];
    float a1 = xin[((size_t)d1.x << 6) + lane];
    sum = fmaf(__int_as_float(d0.y), a0, sum);
    sum = fmaf(__int_as_float(d1.y), a1, sum);
  }
  if (e < e1) {
    int2 d0 = edges[e];
    sum = fmaf(__int_as_float(d0.y), xin[((size_t)d0.x << 6) + lane], sum);
  }
  if (MODE != 2) y[(size_t)r * D + lane] = sum;
  float* acc = (r < N_U) ? (accu + (size_t)r * D + lane)
                         : (acci + (size_t)(r - N_U) * D + lane);
  if (MODE == 0)      *acc = sum;
  else if (MODE == 1) *acc += sum;
  else                *acc = (*acc + sum) * (1.f / 3.f);
}

// ---------------- G1: P = 3 * W(Q x N) @ mean(N x D) ------------------------
__global__ void k_g1(const float* __restrict__ ut, const float* __restrict__ vt,
                     const float* __restrict__ accu, const float* __restrict__ acci,
                     float* __restrict__ P) {
  const float* W = blockIdx.y ? vt : ut;     // (Q, N_U) row-major
  const float* X = blockIdx.y ? acci : accu; // (N_U, D) -- holds mean = acc/3
  float* out = P + (size_t)blockIdx.y * (Q * D);
  const int t = threadIdx.x;
  const int d = t & 63;
  const int qg = t >> 6;                     // 4 q-groups of 32
  const int n0 = blockIdx.x * 256;
  const int n1 = min(n0 + 256, N_U);
  float acc[32];
#pragma unroll
  for (int i = 0; i < 32; ++i) acc[i] = 0.f;
  for (int n = n0; n < n1; n += 4) {
    float x0 = X[(size_t)(n + 0) * D + d];
    float x1 = X[(size_t)(n + 1) * D + d];
    float x2 = X[(size_t)(n + 2) * D + d];
    float x3 = X[(size_t)(n + 3) * D + d];
#pragma unroll
    for (int i = 0; i < 32; ++i) {
      const int q = qg * 32 + i;
      float4 w = *reinterpret_cast<const float4*>(W + (size_t)q * N_U + n);
      acc[i] = fmaf(w.x, x0, acc[i]);
      acc[i] = fmaf(w.y, x1, acc[i]);
      acc[i] = fmaf(w.z, x2, acc[i]);
      acc[i] = fmaf(w.w, x3, acc[i]);
    }
  }
  // fold the *3 (acc holds mean = Σ/3, SVD path needs Σ)
#pragma unroll
  for (int i = 0; i < 32; ++i) atomicAdd(&out[(qg * 32 + i) * D + d], acc[i] * 3.f);
}

// ---------------- G2: out(N x D) = M(N x Q) @ P(Q x D), P in registers ------
__global__ void __launch_bounds__(256) k_g2(const float* __restrict__ M,
                                            const float* __restrict__ Pg,
                                            float* __restrict__ out) {
  const int d = threadIdx.x & 63;
  float p[Q];
#pragma unroll
  for (int q = 0; q < Q; ++q) p[q] = Pg[q * D + d];
  const int w = (blockIdx.x * 256 + threadIdx.x) >> 6;
  const int nw = (gridDim.x * 256) >> 6;
  for (int r = w; r < N_U; r += nw) {
    const float4* mrow = reinterpret_cast<const float4*>(M + (size_t)r * Q);
    float sum = 0.f;
#pragma unroll
    for (int q4 = 0; q4 < 32; ++q4) {
      float4 m = mrow[q4];
      sum = fmaf(m.x, p[4 * q4 + 0], sum);
      sum = fmaf(m.y, p[4 * q4 + 1], sum);
      sum = fmaf(m.z, p[4 * q4 + 2], sum);
      sum = fmaf(m.w, p[4 * q4 + 3], sum);
    }
    out[(size_t)r * D + d] = sum;
  }
}

extern "C" void kernel_launch(void* const* d_in, const int* in_sizes, int n_in,
                              void* d_out, int out_size, void* d_ws, size_t ws_size,
                              hipStream_t stream) {
  const float* user_emb = (const float*)d_in[0];
  const float* item_emb = (const float*)d_in[1];
  const int*   adj_row  = (const int*)d_in[2];
  const int*   adj_col  = (const int*)d_in[3];
  const float* adj_vals = (const float*)d_in[4];
  const float* ut       = (const float*)d_in[5];
  const float* vt       = (const float*)d_in[6];
  const float* u_mul_s  = (const float*)d_in[7];
  const float* v_mul_s  = (const float*)d_in[8];
  float* out = (float*)d_out;

  char* ws = (char*)d_ws;
  size_t off = 0;
  auto alloc = [&](size_t bytes) -> void* {
    void* p = ws + off;
    off = (off + bytes + 255) & ~(size_t)255;
    return p;
  };
  float* x      = (float*)alloc((size_t)NTOT * D * 4);   // 51.2 MB
  float* yb     = (float*)alloc((size_t)NTOT * D * 4);   // 51.2 MB
  int2*  edges  = (int2*)alloc((size_t)NNZ * 8);         // 25.6 MB interleaved
  int*   rowptr = (int*)alloc((size_t)(NTOT + 1) * 4);
  int*   fill   = (int*)alloc((size_t)NTOT * 4);
  int*   cnt    = (int*)alloc((size_t)NTOT * 4);
  int*   bsum   = (int*)alloc(1024);
  float* P      = (float*)alloc(2 * Q * D * 4);          // P[0]=ut@acc_u, P[1]=vt@acc_i

  float* acc_u = out;                    // seg0 -> mean_u
  float* svd_u = out + (size_t)SEG;      // seg1
  float* acc_i = out + 2 * (size_t)SEG;  // seg2 -> mean_i
  float* svd_i = out + 3 * (size_t)SEG;  // seg3

  hipMemsetAsync(cnt, 0, (size_t)NTOT * 4, stream);
  hipMemsetAsync(P, 0, 2 * Q * D * 4, stream);
  // contiguous ego-embedding buffer (single gather base for all layers)
  hipMemcpyAsync(x, user_emb, (size_t)SEG * 4, hipMemcpyDeviceToDevice, stream);
  hipMemcpyAsync(x + (size_t)SEG, item_emb, (size_t)SEG * 4, hipMemcpyDeviceToDevice,
                 stream);

  k_hist<<<(NNZ + 255) / 256, 256, 0, stream>>>(adj_row, cnt);
  k_scanA<<<98, 256, 0, stream>>>(cnt, rowptr, bsum);
  k_scanB<<<1, 128, 0, stream>>>(bsum, 98);
  k_scanC<<<(NTOT + 256) / 256, 256, 0, stream>>>(bsum, rowptr, fill);
  k_scatter<<<(NNZ + 255) / 256, 256, 0, stream>>>(adj_row, adj_col, adj_vals, fill,
                                                   edges);

  const int spmmGrid = (NTOT * 64) / 256;
  k_spmm<0><<<spmmGrid, 256, 0, stream>>>(rowptr, edges, x, yb, acc_u, acc_i);
  k_spmm<1><<<spmmGrid, 256, 0, stream>>>(rowptr, edges, yb, x, acc_u, acc_i);
  k_spmm<2><<<spmmGrid, 256, 0, stream>>>(rowptr, edges, x, nullptr, acc_u, acc_i);

  // P_u = 3 * ut @ mean_u (y=0), P_v = 3 * vt @ mean_i (y=1)
  k_g1<<<dim3(391, 2), 256, 0, stream>>>(ut, vt, acc_u, acc_i, P);

  // svd_u = u_mul_s @ P_v ; svd_i = v_mul_s @ P_u
  k_g2<<<2048, 256, 0, stream>>>(u_mul_s, P + Q * D, svd_u);
  k_g2<<<2048, 256, 0, stream>>>(v_mul_s, P, svd_i);
}

// Round 3
// 1181.391 us; speedup vs baseline: 1.7897x; 1.3698x over previous
//
#include <hip/hip_runtime.h>

constexpr int N_U  = 100000;
constexpr int N_I  = 100000;
constexpr int NTOT = 200000;   // N_U + N_I
constexpr int D    = 64;
constexpr int Q    = 128;
constexpr int NNZ  = 3200000;
constexpr int SEG  = N_U * D;  // 6,400,000 floats per output segment

constexpr int G1_CHUNK = 400;
constexpr int G1_NBLK  = 250;  // ceil(100000/400)

// ---------------- CSR build ----------------
__global__ void k_hist(const int* __restrict__ row, int* __restrict__ cnt) {
  int e = blockIdx.x * 256 + threadIdx.x;
  if (e < NNZ) atomicAdd(&cnt[row[e]], 1);
}

__global__ void k_scanA(const int* __restrict__ cnt, int* __restrict__ rowptr,
                        int* __restrict__ bsum) {
  __shared__ int s[256];
  const int t = threadIdx.x;
  const int base = blockIdx.x * 2048 + t * 8;
  int v[8];
  int sum = 0;
#pragma unroll
  for (int i = 0; i < 8; ++i) {
    int idx = base + i;
    int c = (idx < NTOT) ? cnt[idx] : 0;
    v[i] = sum;
    sum += c;
  }
  s[t] = sum;
  __syncthreads();
  const int own = sum;
  for (int off = 1; off < 256; off <<= 1) {
    int y = (t >= off) ? s[t - off] : 0;
    __syncthreads();
    s[t] += y;
    __syncthreads();
  }
  int excl = s[t] - own;
  if (t == 255) bsum[blockIdx.x] = s[255];
#pragma unroll
  for (int i = 0; i < 8; ++i) {
    int idx = base + i;
    if (idx < NTOT) rowptr[idx] = excl + v[i];
  }
}

__global__ void k_scanB(int* __restrict__ bsum, int nblk) {
  __shared__ int s[128];
  const int t = threadIdx.x;
  int v = (t < nblk) ? bsum[t] : 0;
  s[t] = v;
  __syncthreads();
  for (int off = 1; off < 128; off <<= 1) {
    int y = (t >= off) ? s[t - off] : 0;
    __syncthreads();
    s[t] += y;
    __syncthreads();
  }
  if (t < nblk) bsum[t] = s[t] - v;
}

__global__ void k_scanC(const int* __restrict__ bsum, int* __restrict__ rowptr,
                        int* __restrict__ fill) {
  int i = blockIdx.x * 256 + threadIdx.x;
  if (i < NTOT) {
    int v = rowptr[i] + bsum[i >> 11];
    rowptr[i] = v;
    fill[i] = v;
  } else if (i == NTOT) {
    rowptr[NTOT] = NNZ;
  }
}

__global__ void k_scatter(const int* __restrict__ row, const int* __restrict__ col,
                          const float* __restrict__ val, int* __restrict__ fill,
                          int2* __restrict__ edges) {
  int e = blockIdx.x * 256 + threadIdx.x;
  if (e < NNZ) {
    int r = row[e];
    int p = atomicAdd(&fill[r], 1);
    edges[p] = make_int2(col[e], __float_as_int(val[e]));
  }
}

// ---------------- SpMM (gather, wave per row, lane = d, 8-deep MLP) ---------
// MODE 0: y = sum, acc = sum           (layer 1, initializes acc)
// MODE 1: y = sum, acc += sum          (layer 2)
// MODE 2: no y,    acc = (acc+sum)/3   (layer 3, fused mean)
template <int MODE>
__global__ void k_spmm(const int* __restrict__ rowptr, const int2* __restrict__ edges,
                       const float* __restrict__ xin, float* __restrict__ y,
                       float* __restrict__ accu, float* __restrict__ acci) {
  const int r = (blockIdx.x * 256 + threadIdx.x) >> 6;
  const int lane = threadIdx.x & 63;
  if (r >= NTOT) return;
  const int e0 = rowptr[r], e1 = rowptr[r + 1];
  float sum = 0.f;
  int e = e0;
  for (; e + 8 <= e1; e += 8) {
    int2 d0 = edges[e + 0], d1 = edges[e + 1], d2 = edges[e + 2], d3 = edges[e + 3];
    int2 d4 = edges[e + 4], d5 = edges[e + 5], d6 = edges[e + 6], d7 = edges[e + 7];
    float a0 = xin[((size_t)d0.x << 6) + lane];
    float a1 = xin[((size_t)d1.x << 6) + lane];
    float a2 = xin[((size_t)d2.x << 6) + lane];
    float a3 = xin[((size_t)d3.x << 6) + lane];
    float a4 = xin[((size_t)d4.x << 6) + lane];
    float a5 = xin[((size_t)d5.x << 6) + lane];
    float a6 = xin[((size_t)d6.x << 6) + lane];
    float a7 = xin[((size_t)d7.x << 6) + lane];
    sum = fmaf(__int_as_float(d0.y), a0, sum);
    sum = fmaf(__int_as_float(d1.y), a1, sum);
    sum = fmaf(__int_as_float(d2.y), a2, sum);
    sum = fmaf(__int_as_float(d3.y), a3, sum);
    sum = fmaf(__int_as_float(d4.y), a4, sum);
    sum = fmaf(__int_as_float(d5.y), a5, sum);
    sum = fmaf(__int_as_float(d6.y), a6, sum);
    sum = fmaf(__int_as_float(d7.y), a7, sum);
  }
  for (; e + 2 <= e1; e += 2) {
    int2 d0 = edges[e + 0], d1 = edges[e + 1];
    float a0 = xin[((size_t)d0.x << 6) + lane];
    float a1 = xin[((size_t)d1.x << 6) + lane];
    sum = fmaf(__int_as_float(d0.y), a0, sum);
    sum = fmaf(__int_as_float(d1.y), a1, sum);
  }
  if (e < e1) {
    int2 d0 = edges[e];
    sum = fmaf(__int_as_float(d0.y), xin[((size_t)d0.x << 6) + lane], sum);
  }
  if (MODE != 2) y[(size_t)r * D + lane] = sum;
  float* acc = (r < N_U) ? (accu + (size_t)r * D + lane)
                         : (acci + (size_t)(r - N_U) * D + lane);
  if (MODE == 0)      *acc = sum;
  else if (MODE == 1) *acc += sum;
  else                *acc = (*acc + sum) * (1.f / 3.f);
}

// ---------------- G1: Ppart[mat][blk] = W(128 x nchunk) @ X(nchunk x 64) ----
// LDS-tiled, 512 threads, thread owns 4q x 4d register tile. No atomics:
// per-block partials, reduced by k_reduce.
__global__ void __launch_bounds__(512) k_g1(const float* __restrict__ ut,
                                            const float* __restrict__ vt,
                                            const float* __restrict__ accu,
                                            const float* __restrict__ acci,
                                            float* __restrict__ Ppart) {
  __shared__ float Wl[128 * 65];
  __shared__ float Xl[64 * 64];
  const int mat = blockIdx.y;
  const float* __restrict__ W = mat ? vt : ut;    // (Q, N_U) row-major
  const float* __restrict__ X = mat ? acci : accu;  // (N_U, 64) holds mean
  const int t = threadIdx.x;
  const int q0 = (t >> 4) * 4;   // 32 q-groups
  const int d0 = (t & 15) * 4;   // 16 d-groups
  const int n0 = blockIdx.x * G1_CHUNK;
  const int n1 = min(n0 + G1_CHUNK, N_U);
  float4 a0 = {0, 0, 0, 0}, a1 = {0, 0, 0, 0}, a2 = {0, 0, 0, 0}, a3 = {0, 0, 0, 0};
  for (int k = n0; k < n1; k += 64) {
    // stage X[k..k+64][0..64] -> Xl (1024 float4, 2 per thread)
#pragma unroll
    for (int rep = 0; rep < 2; ++rep) {
      int f4 = t + rep * 512;
      int row = f4 >> 4;
      int c4 = (f4 & 15) * 4;
      int gr = k + row;
      float4 v = (gr < n1) ? *reinterpret_cast<const float4*>(X + (size_t)gr * 64 + c4)
                           : float4{0, 0, 0, 0};
      *reinterpret_cast<float4*>(&Xl[row * 64 + c4]) = v;
    }
    // stage W[0..128][k..k+64] -> Wl[q][kk] (2048 float4, 4 per thread)
    {
      int q = t >> 2;
      int c16 = (t & 3) * 16;
#pragma unroll
      for (int jj = 0; jj < 4; ++jj) {
        int kk = c16 + jj * 4;
        int gk = k + kk;
        float4 v = (gk < n1) ? *reinterpret_cast<const float4*>(W + (size_t)q * N_U + gk)
                             : float4{0, 0, 0, 0};
        *reinterpret_cast<float4*>(&Wl[q * 65 + kk]) = v;
      }
    }
    __syncthreads();
#pragma unroll 2
    for (int kk = 0; kk < 64; kk += 4) {
      float4 w0 = *reinterpret_cast<const float4*>(&Wl[(q0 + 0) * 65 + kk]);
      float4 w1 = *reinterpret_cast<const float4*>(&Wl[(q0 + 1) * 65 + kk]);
      float4 w2 = *reinterpret_cast<const float4*>(&Wl[(q0 + 2) * 65 + kk]);
      float4 w3 = *reinterpret_cast<const float4*>(&Wl[(q0 + 3) * 65 + kk]);
      float4 x0 = *reinterpret_cast<const float4*>(&Xl[(kk + 0) * 64 + d0]);
      float4 x1 = *reinterpret_cast<const float4*>(&Xl[(kk + 1) * 64 + d0]);
      float4 x2 = *reinterpret_cast<const float4*>(&Xl[(kk + 2) * 64 + d0]);
      float4 x3 = *reinterpret_cast<const float4*>(&Xl[(kk + 3) * 64 + d0]);
#define FMA16(aj, wj)                                                                 \
  aj.x = fmaf(wj.x, x0.x, aj.x); aj.y = fmaf(wj.x, x0.y, aj.y);                       \
  aj.z = fmaf(wj.x, x0.z, aj.z); aj.w = fmaf(wj.x, x0.w, aj.w);                       \
  aj.x = fmaf(wj.y, x1.x, aj.x); aj.y = fmaf(wj.y, x1.y, aj.y);                       \
  aj.z = fmaf(wj.y, x1.z, aj.z); aj.w = fmaf(wj.y, x1.w, aj.w);                       \
  aj.x = fmaf(wj.z, x2.x, aj.x); aj.y = fmaf(wj.z, x2.y, aj.y);                       \
  aj.z = fmaf(wj.z, x2.z, aj.z); aj.w = fmaf(wj.z, x2.w, aj.w);                       \
  aj.x = fmaf(wj.w, x3.x, aj.x); aj.y = fmaf(wj.w, x3.y, aj.y);                       \
  aj.z = fmaf(wj.w, x3.z, aj.z); aj.w = fmaf(wj.w, x3.w, aj.w);
      FMA16(a0, w0)
      FMA16(a1, w1)
      FMA16(a2, w2)
      FMA16(a3, w3)
#undef FMA16
    }
    __syncthreads();
  }
  float* dst = Ppart + ((size_t)mat * G1_NBLK + blockIdx.x) * (Q * D);
  *reinterpret_cast<float4*>(dst + (q0 + 0) * 64 + d0) = a0;
  *reinterpret_cast<float4*>(dst + (q0 + 1) * 64 + d0) = a1;
  *reinterpret_cast<float4*>(dst + (q0 + 2) * 64 + d0) = a2;
  *reinterpret_cast<float4*>(dst + (q0 + 3) * 64 + d0) = a3;
}

// P[mat][q][d] = 3 * sum_blk Ppart[mat][blk][q][d]   (x3: SVD path needs Sigma, not mean)
__global__ void k_reduce(const float* __restrict__ Ppart, float* __restrict__ P) {
  int idx = blockIdx.x * 256 + threadIdx.x;  // 0..16383
  if (idx >= 2 * Q * D) return;
  int mat = idx >> 13;
  int qd = idx & (Q * D - 1);
  const float* src = Ppart + (size_t)mat * G1_NBLK * (Q * D) + qd;
  float s = 0.f;
#pragma unroll 4
  for (int b = 0; b < G1_NBLK; ++b) s += src[(size_t)b * (Q * D)];
  P[idx] = s * 3.f;
}

// ---------------- G2: svd_u = u_mul_s @ P_v ; svd_i = v_mul_s @ P_u ---------
__global__ void __launch_bounds__(256) k_g2(const float* __restrict__ u_mul_s,
                                            const float* __restrict__ v_mul_s,
                                            const float* __restrict__ P,
                                            float* __restrict__ svd_u,
                                            float* __restrict__ svd_i) {
  const float* __restrict__ M  = blockIdx.y ? v_mul_s : u_mul_s;  // (N_U, Q)
  const float* __restrict__ Pg = blockIdx.y ? P : (P + Q * D);
  float* __restrict__ out      = blockIdx.y ? svd_i : svd_u;
  const int d = threadIdx.x & 63;
  float4 p4[32];
#pragma unroll
  for (int q4 = 0; q4 < 32; ++q4)
    p4[q4] = make_float4(Pg[(4 * q4 + 0) * 64 + d], Pg[(4 * q4 + 1) * 64 + d],
                         Pg[(4 * q4 + 2) * 64 + d], Pg[(4 * q4 + 3) * 64 + d]);
  const int w = (blockIdx.x * 256 + threadIdx.x) >> 6;
  const int nw = (gridDim.x * 256) >> 6;
  for (int r0 = w; r0 < N_U; r0 += 2 * nw) {
    const int r1 = r0 + nw;
    const float4* m0 = reinterpret_cast<const float4*>(M + (size_t)r0 * Q);
    const float4* m1 = (r1 < N_U) ? reinterpret_cast<const float4*>(M + (size_t)r1 * Q) : m0;
    float s0[4] = {0, 0, 0, 0}, s1[4] = {0, 0, 0, 0};
#pragma unroll
    for (int q4 = 0; q4 < 32; ++q4) {
      float4 a = m0[q4];
      float4 b = m1[q4];
      float4 p = p4[q4];
      const int j = q4 & 3;
      s0[j] = fmaf(a.x, p.x, s0[j]); s0[j] = fmaf(a.y, p.y, s0[j]);
      s0[j] = fmaf(a.z, p.z, s0[j]); s0[j] = fmaf(a.w, p.w, s0[j]);
      s1[j] = fmaf(b.x, p.x, s1[j]); s1[j] = fmaf(b.y, p.y, s1[j]);
      s1[j] = fmaf(b.z, p.z, s1[j]); s1[j] = fmaf(b.w, p.w, s1[j]);
    }
    out[(size_t)r0 * 64 + d] = (s0[0] + s0[1]) + (s0[2] + s0[3]);
    if (r1 < N_U) out[(size_t)r1 * 64 + d] = (s1[0] + s1[1]) + (s1[2] + s1[3]);
  }
}

extern "C" void kernel_launch(void* const* d_in, const int* in_sizes, int n_in,
                              void* d_out, int out_size, void* d_ws, size_t ws_size,
                              hipStream_t stream) {
  const float* user_emb = (const float*)d_in[0];
  const float* item_emb = (const float*)d_in[1];
  const int*   adj_row  = (const int*)d_in[2];
  const int*   adj_col  = (const int*)d_in[3];
  const float* adj_vals = (const float*)d_in[4];
  const float* ut       = (const float*)d_in[5];
  const float* vt       = (const float*)d_in[6];
  const float* u_mul_s  = (const float*)d_in[7];
  const float* v_mul_s  = (const float*)d_in[8];
  float* out = (float*)d_out;

  char* ws = (char*)d_ws;
  size_t off = 0;
  auto alloc = [&](size_t bytes) -> void* {
    void* p = ws + off;
    off = (off + bytes + 255) & ~(size_t)255;
    return p;
  };
  float* x      = (float*)alloc((size_t)NTOT * D * 4);            // 51.2 MB
  float* yb     = (float*)alloc((size_t)NTOT * D * 4);            // 51.2 MB
  int2*  edges  = (int2*)alloc((size_t)NNZ * 8);                  // 25.6 MB
  int*   rowptr = (int*)alloc((size_t)(NTOT + 1) * 4);
  int*   fill   = (int*)alloc((size_t)NTOT * 4);
  int*   cnt    = (int*)alloc((size_t)NTOT * 4);
  int*   bsum   = (int*)alloc(1024);
  float* P      = (float*)alloc(2 * Q * D * 4);                   // 64 KB
  float* Ppart  = (float*)alloc((size_t)2 * G1_NBLK * Q * D * 4); // 16.4 MB

  float* acc_u = out;                    // seg0 -> mean_u
  float* svd_u = out + (size_t)SEG;      // seg1
  float* acc_i = out + 2 * (size_t)SEG;  // seg2 -> mean_i
  float* svd_i = out + 3 * (size_t)SEG;  // seg3

  hipMemsetAsync(cnt, 0, (size_t)NTOT * 4, stream);
  // contiguous ego-embedding buffer (single gather base for all layers)
  hipMemcpyAsync(x, user_emb, (size_t)SEG * 4, hipMemcpyDeviceToDevice, stream);
  hipMemcpyAsync(x + (size_t)SEG, item_emb, (size_t)SEG * 4, hipMemcpyDeviceToDevice,
                 stream);

  k_hist<<<(NNZ + 255) / 256, 256, 0, stream>>>(adj_row, cnt);
  k_scanA<<<98, 256, 0, stream>>>(cnt, rowptr, bsum);
  k_scanB<<<1, 128, 0, stream>>>(bsum, 98);
  k_scanC<<<(NTOT + 256) / 256, 256, 0, stream>>>(bsum, rowptr, fill);
  k_scatter<<<(NNZ + 255) / 256, 256, 0, stream>>>(adj_row, adj_col, adj_vals, fill,
                                                   edges);

  const int spmmGrid = (NTOT * 64) / 256;
  k_spmm<0><<<spmmGrid, 256, 0, stream>>>(rowptr, edges, x, yb, acc_u, acc_i);
  k_spmm<1><<<spmmGrid, 256, 0, stream>>>(rowptr, edges, yb, x, acc_u, acc_i);
  k_spmm<2><<<spmmGrid, 256, 0, stream>>>(rowptr, edges, x, nullptr, acc_u, acc_i);

  // P_u partials (y=0, from mean_u/ut), P_v partials (y=1, from mean_i/vt)
  k_g1<<<dim3(G1_NBLK, 2), 512, 0, stream>>>(ut, vt, acc_u, acc_i, Ppart);
  k_reduce<<<(2 * Q * D + 255) / 256, 256, 0, stream>>>(Ppart, P);

  // y=0: svd_u = u_mul_s @ P_v ; y=1: svd_i = v_mul_s @ P_u
  k_g2<<<dim3(512, 2), 256, 0, stream>>>(u_mul_s, v_mul_s, P, svd_u, svd_i);
}

// Round 4
// 1047.237 us; speedup vs baseline: 2.0190x; 1.1281x over previous
//
#include <hip/hip_runtime.h>

constexpr int N_U  = 100000;
constexpr int N_I  = 100000;
constexpr int NTOT = 200000;   // N_U + N_I
constexpr int D    = 64;
constexpr int Q    = 128;
constexpr int NNZ  = 3200000;
constexpr int SEG  = N_U * D;  // 6,400,000 floats per output segment

constexpr int G1_CHUNK = 400;
constexpr int G1_NBLK  = 250;  // ceil(100000/400)

// ---------------- CSR build ----------------
__global__ void k_hist(const int* __restrict__ row, int* __restrict__ cnt) {
  int e = blockIdx.x * 256 + threadIdx.x;
  if (e < NNZ) atomicAdd(&cnt[row[e]], 1);
}

__global__ void k_scanA(const int* __restrict__ cnt, int* __restrict__ rowptr,
                        int* __restrict__ bsum) {
  __shared__ int s[256];
  const int t = threadIdx.x;
  const int base = blockIdx.x * 2048 + t * 8;
  int v[8];
  int sum = 0;
#pragma unroll
  for (int i = 0; i < 8; ++i) {
    int idx = base + i;
    int c = (idx < NTOT) ? cnt[idx] : 0;
    v[i] = sum;
    sum += c;
  }
  s[t] = sum;
  __syncthreads();
  const int own = sum;
  for (int off = 1; off < 256; off <<= 1) {
    int y = (t >= off) ? s[t - off] : 0;
    __syncthreads();
    s[t] += y;
    __syncthreads();
  }
  int excl = s[t] - own;
  if (t == 255) bsum[blockIdx.x] = s[255];
#pragma unroll
  for (int i = 0; i < 8; ++i) {
    int idx = base + i;
    if (idx < NTOT) rowptr[idx] = excl + v[i];
  }
}

__global__ void k_scanB(int* __restrict__ bsum, int nblk) {
  __shared__ int s[128];
  const int t = threadIdx.x;
  int v = (t < nblk) ? bsum[t] : 0;
  s[t] = v;
  __syncthreads();
  for (int off = 1; off < 128; off <<= 1) {
    int y = (t >= off) ? s[t - off] : 0;
    __syncthreads();
    s[t] += y;
    __syncthreads();
  }
  if (t < nblk) bsum[t] = s[t] - v;
}

__global__ void k_scanC(const int* __restrict__ bsum, int* __restrict__ rowptr,
                        int* __restrict__ fill) {
  int i = blockIdx.x * 256 + threadIdx.x;
  if (i < NTOT) {
    int v = rowptr[i] + bsum[i >> 11];
    rowptr[i] = v;
    fill[i] = v;
  } else if (i == NTOT) {
    rowptr[NTOT] = NNZ;
  }
}

__global__ void k_scatter(const int* __restrict__ row, const int* __restrict__ col,
                          const float* __restrict__ val, int* __restrict__ fill,
                          int2* __restrict__ edges) {
  int e = blockIdx.x * 256 + threadIdx.x;
  if (e < NNZ) {
    int r = row[e];
    int p = atomicAdd(&fill[r], 1);
    edges[p] = make_int2(col[e], __float_as_int(val[e]));
  }
}

// ---------------- SpMM (gather, wave per row, lane = d, 8-deep MLP) ---------
// xu: base for cols < N_U ; xim: base already offset so xim + (c<<6) is valid
// for cols >= N_U (i.e. xim = item_base - N_U*64). For contiguous layer
// buffers pass xu == xim == buffer.
// MODE 0: y = sum, acc = sum           (layer 1, initializes acc)
// MODE 1: y = sum, acc += sum          (layer 2)
// MODE 2: no y,    acc = (acc+sum)/3   (layer 3, fused mean)
template <int MODE>
__global__ void k_spmm(const int* __restrict__ rowptr, const int2* __restrict__ edges,
                       const float* __restrict__ xu, const float* __restrict__ xim,
                       float* __restrict__ y,
                       float* __restrict__ accu, float* __restrict__ acci) {
  const int r = (blockIdx.x * 256 + threadIdx.x) >> 6;
  const int lane = threadIdx.x & 63;
  if (r >= NTOT) return;
  const int e0 = rowptr[r], e1 = rowptr[r + 1];
  float sum = 0.f;
  int e = e0;
#define SRC(dd) ((((dd).x < N_U) ? xu : xim) + ((size_t)(dd).x << 6) + lane)
  for (; e + 8 <= e1; e += 8) {
    int2 d0 = edges[e + 0], d1 = edges[e + 1], d2 = edges[e + 2], d3 = edges[e + 3];
    int2 d4 = edges[e + 4], d5 = edges[e + 5], d6 = edges[e + 6], d7 = edges[e + 7];
    float a0 = *SRC(d0);
    float a1 = *SRC(d1);
    float a2 = *SRC(d2);
    float a3 = *SRC(d3);
    float a4 = *SRC(d4);
    float a5 = *SRC(d5);
    float a6 = *SRC(d6);
    float a7 = *SRC(d7);
    sum = fmaf(__int_as_float(d0.y), a0, sum);
    sum = fmaf(__int_as_float(d1.y), a1, sum);
    sum = fmaf(__int_as_float(d2.y), a2, sum);
    sum = fmaf(__int_as_float(d3.y), a3, sum);
    sum = fmaf(__int_as_float(d4.y), a4, sum);
    sum = fmaf(__int_as_float(d5.y), a5, sum);
    sum = fmaf(__int_as_float(d6.y), a6, sum);
    sum = fmaf(__int_as_float(d7.y), a7, sum);
  }
  for (; e + 2 <= e1; e += 2) {
    int2 d0 = edges[e + 0], d1 = edges[e + 1];
    float a0 = *SRC(d0);
    float a1 = *SRC(d1);
    sum = fmaf(__int_as_float(d0.y), a0, sum);
    sum = fmaf(__int_as_float(d1.y), a1, sum);
  }
  if (e < e1) {
    int2 d0 = edges[e];
    sum = fmaf(__int_as_float(d0.y), *SRC(d0), sum);
  }
#undef SRC
  if (MODE != 2) y[(size_t)r * D + lane] = sum;
  float* acc = (r < N_U) ? (accu + (size_t)r * D + lane)
                         : (acci + (size_t)(r - N_U) * D + lane);
  if (MODE == 0)      *acc = sum;
  else if (MODE == 1) *acc += sum;
  else                *acc = (*acc + sum) * (1.f / 3.f);
}

// ---------------- G1: Ppart[mat][blk] = W(128 x nchunk) @ X(nchunk x 64) ----
__global__ void __launch_bounds__(512) k_g1(const float* __restrict__ ut,
                                            const float* __restrict__ vt,
                                            const float* __restrict__ accu,
                                            const float* __restrict__ acci,
                                            float* __restrict__ Ppart) {
  __shared__ float Wl[128 * 65];
  __shared__ float Xl[64 * 64];
  const int mat = blockIdx.y;
  const float* __restrict__ W = mat ? vt : ut;      // (Q, N_U) row-major
  const float* __restrict__ X = mat ? acci : accu;  // (N_U, 64) holds mean
  const int t = threadIdx.x;
  const int q0 = (t >> 4) * 4;   // 32 q-groups
  const int d0 = (t & 15) * 4;   // 16 d-groups
  const int n0 = blockIdx.x * G1_CHUNK;
  const int n1 = min(n0 + G1_CHUNK, N_U);
  float4 a0 = {0, 0, 0, 0}, a1 = {0, 0, 0, 0}, a2 = {0, 0, 0, 0}, a3 = {0, 0, 0, 0};
  for (int k = n0; k < n1; k += 64) {
#pragma unroll
    for (int rep = 0; rep < 2; ++rep) {
      int f4 = t + rep * 512;
      int row = f4 >> 4;
      int c4 = (f4 & 15) * 4;
      int gr = k + row;
      float4 v = (gr < n1) ? *reinterpret_cast<const float4*>(X + (size_t)gr * 64 + c4)
                           : float4{0, 0, 0, 0};
      *reinterpret_cast<float4*>(&Xl[row * 64 + c4]) = v;
    }
    {
      int q = t >> 2;
      int c16 = (t & 3) * 16;
#pragma unroll
      for (int jj = 0; jj < 4; ++jj) {
        int kk = c16 + jj * 4;
        int gk = k + kk;
        float4 v = (gk < n1) ? *reinterpret_cast<const float4*>(W + (size_t)q * N_U + gk)
                             : float4{0, 0, 0, 0};
        *reinterpret_cast<float4*>(&Wl[q * 65 + kk]) = v;
      }
    }
    __syncthreads();
#pragma unroll 2
    for (int kk = 0; kk < 64; kk += 4) {
      float4 w0 = *reinterpret_cast<const float4*>(&Wl[(q0 + 0) * 65 + kk]);
      float4 w1 = *reinterpret_cast<const float4*>(&Wl[(q0 + 1) * 65 + kk]);
      float4 w2 = *reinterpret_cast<const float4*>(&Wl[(q0 + 2) * 65 + kk]);
      float4 w3 = *reinterpret_cast<const float4*>(&Wl[(q0 + 3) * 65 + kk]);
      float4 x0 = *reinterpret_cast<const float4*>(&Xl[(kk + 0) * 64 + d0]);
      float4 x1 = *reinterpret_cast<const float4*>(&Xl[(kk + 1) * 64 + d0]);
      float4 x2 = *reinterpret_cast<const float4*>(&Xl[(kk + 2) * 64 + d0]);
      float4 x3 = *reinterpret_cast<const float4*>(&Xl[(kk + 3) * 64 + d0]);
#define FMA16(aj, wj)                                                                 \
  aj.x = fmaf(wj.x, x0.x, aj.x); aj.y = fmaf(wj.x, x0.y, aj.y);                       \
  aj.z = fmaf(wj.x, x0.z, aj.z); aj.w = fmaf(wj.x, x0.w, aj.w);                       \
  aj.x = fmaf(wj.y, x1.x, aj.x); aj.y = fmaf(wj.y, x1.y, aj.y);                       \
  aj.z = fmaf(wj.y, x1.z, aj.z); aj.w = fmaf(wj.y, x1.w, aj.w);                       \
  aj.x = fmaf(wj.z, x2.x, aj.x); aj.y = fmaf(wj.z, x2.y, aj.y);                       \
  aj.z = fmaf(wj.z, x2.z, aj.z); aj.w = fmaf(wj.z, x2.w, aj.w);                       \
  aj.x = fmaf(wj.w, x3.x, aj.x); aj.y = fmaf(wj.w, x3.y, aj.y);                       \
  aj.z = fmaf(wj.w, x3.z, aj.z); aj.w = fmaf(wj.w, x3.w, aj.w);
      FMA16(a0, w0)
      FMA16(a1, w1)
      FMA16(a2, w2)
      FMA16(a3, w3)
#undef FMA16
    }
    __syncthreads();
  }
  float* dst = Ppart + ((size_t)mat * G1_NBLK + blockIdx.x) * (Q * D);
  *reinterpret_cast<float4*>(dst + (q0 + 0) * 64 + d0) = a0;
  *reinterpret_cast<float4*>(dst + (q0 + 1) * 64 + d0) = a1;
  *reinterpret_cast<float4*>(dst + (q0 + 2) * 64 + d0) = a2;
  *reinterpret_cast<float4*>(dst + (q0 + 3) * 64 + d0) = a3;
}

// P[mat][q][d] = 3 * sum_blk Ppart[mat][blk][q][d]
__global__ void k_reduce(const float* __restrict__ Ppart, float* __restrict__ P) {
  int idx = blockIdx.x * 256 + threadIdx.x;  // 0..16383
  if (idx >= 2 * Q * D) return;
  int mat = idx >> 13;
  int qd = idx & (Q * D - 1);
  const float* src = Ppart + (size_t)mat * G1_NBLK * (Q * D) + qd;
  float s = 0.f;
#pragma unroll 4
  for (int b = 0; b < G1_NBLK; ++b) s += src[(size_t)b * (Q * D)];
  P[idx] = s * 3.f;
}

// ---------------- G2: svd_u = u_mul_s @ P_v ; svd_i = v_mul_s @ P_u ---------
// Wave-uniform row base forced into SGPRs via readfirstlane so the fully
// unrolled 32 float4 row loads become scalar (K$) loads; FMAs read one SGPR
// operand each. Lane = d; P column lives in 128 VGPRs.
__global__ void __launch_bounds__(256) k_g2(const float* __restrict__ u_mul_s,
                                            const float* __restrict__ v_mul_s,
                                            const float* __restrict__ P,
                                            float* __restrict__ svd_u,
                                            float* __restrict__ svd_i) {
  const int mat = blockIdx.y;
  const float* __restrict__ M  = mat ? v_mul_s : u_mul_s;  // (N_U, Q)
  const float* __restrict__ Pg = mat ? P : (P + Q * D);
  float* __restrict__ out      = mat ? svd_i : svd_u;
  const int d = threadIdx.x & 63;
  float4 p4[32];
#pragma unroll
  for (int q4 = 0; q4 < 32; ++q4)
    p4[q4] = make_float4(Pg[(4 * q4 + 0) * 64 + d], Pg[(4 * q4 + 1) * 64 + d],
                         Pg[(4 * q4 + 2) * 64 + d], Pg[(4 * q4 + 3) * 64 + d]);
  const int w = blockIdx.x * 4 + (threadIdx.x >> 6);
  const int nw = gridDim.x * 4;
  for (int r = w; r < N_U; r += nw) {
    const int ru = __builtin_amdgcn_readfirstlane(r);
    const float4* __restrict__ mrow =
        reinterpret_cast<const float4*>(M + (size_t)ru * Q);
    float s0 = 0.f, s1 = 0.f, s2 = 0.f, s3 = 0.f;
#pragma unroll
    for (int q4 = 0; q4 < 32; ++q4) {
      float4 m = mrow[q4];  // wave-uniform address -> scalar load
      s0 = fmaf(m.x, p4[q4].x, s0);
      s1 = fmaf(m.y, p4[q4].y, s1);
      s2 = fmaf(m.z, p4[q4].z, s2);
      s3 = fmaf(m.w, p4[q4].w, s3);
    }
    out[(size_t)ru * D + d] = (s0 + s1) + (s2 + s3);
  }
}

extern "C" void kernel_launch(void* const* d_in, const int* in_sizes, int n_in,
                              void* d_out, int out_size, void* d_ws, size_t ws_size,
                              hipStream_t stream) {
  const float* user_emb = (const float*)d_in[0];
  const float* item_emb = (const float*)d_in[1];
  const int*   adj_row  = (const int*)d_in[2];
  const int*   adj_col  = (const int*)d_in[3];
  const float* adj_vals = (const float*)d_in[4];
  const float* ut       = (const float*)d_in[5];
  const float* vt       = (const float*)d_in[6];
  const float* u_mul_s  = (const float*)d_in[7];
  const float* v_mul_s  = (const float*)d_in[8];
  float* out = (float*)d_out;

  char* ws = (char*)d_ws;
  size_t off = 0;
  auto alloc = [&](size_t bytes) -> void* {
    void* p = ws + off;
    off = (off + bytes + 255) & ~(size_t)255;
    return p;
  };
  float* xb     = (float*)alloc((size_t)NTOT * D * 4);            // 51.2 MB
  float* yb     = (float*)alloc((size_t)NTOT * D * 4);            // 51.2 MB
  int2*  edges  = (int2*)alloc((size_t)NNZ * 8);                  // 25.6 MB
  int*   rowptr = (int*)alloc((size_t)(NTOT + 1) * 4);
  int*   fill   = (int*)alloc((size_t)NTOT * 4);
  int*   cnt    = (int*)alloc((size_t)NTOT * 4);
  int*   bsum   = (int*)alloc(1024);
  float* P      = (float*)alloc(2 * Q * D * 4);                   // 64 KB
  float* Ppart  = (float*)alloc((size_t)2 * G1_NBLK * Q * D * 4); // 16.4 MB

  float* acc_u = out;                    // seg0 -> mean_u
  float* svd_u = out + (size_t)SEG;      // seg1
  float* acc_i = out + 2 * (size_t)SEG;  // seg2 -> mean_i
  float* svd_i = out + 3 * (size_t)SEG;  // seg3

  hipMemsetAsync(cnt, 0, (size_t)NTOT * 4, stream);

  k_hist<<<(NNZ + 255) / 256, 256, 0, stream>>>(adj_row, cnt);
  k_scanA<<<98, 256, 0, stream>>>(cnt, rowptr, bsum);
  k_scanB<<<1, 128, 0, stream>>>(bsum, 98);
  k_scanC<<<(NTOT + 256) / 256, 256, 0, stream>>>(bsum, rowptr, fill);
  k_scatter<<<(NNZ + 255) / 256, 256, 0, stream>>>(adj_row, adj_col, adj_vals, fill,
                                                   edges);

  const int spmmGrid = (NTOT * 64) / 256;
  // layer 1: gather straight from the two input embedding arrays
  const float* item_off = (const float*)((const char*)item_emb - (size_t)SEG * 4);
  k_spmm<0><<<spmmGrid, 256, 0, stream>>>(rowptr, edges, user_emb, item_off, yb,
                                          acc_u, acc_i);
  // layer 2: yb -> xb (contiguous)
  k_spmm<1><<<spmmGrid, 256, 0, stream>>>(rowptr, edges, yb, yb, xb, acc_u, acc_i);
  // layer 3: xb -> (no y), fused mean
  k_spmm<2><<<spmmGrid, 256, 0, stream>>>(rowptr, edges, xb, xb, nullptr, acc_u, acc_i);

  // P_u partials (y=0, from mean_u/ut), P_v partials (y=1, from mean_i/vt)
  k_g1<<<dim3(G1_NBLK, 2), 512, 0, stream>>>(ut, vt, acc_u, acc_i, Ppart);
  k_reduce<<<(2 * Q * D + 255) / 256, 256, 0, stream>>>(Ppart, P);

  // y=0: svd_u = u_mul_s @ P_v ; y=1: svd_i = v_mul_s @ P_u
  k_g2<<<dim3(2048, 2), 256, 0, stream>>>(u_mul_s, v_mul_s, P, svd_u, svd_i);
}

// Round 5
// 793.743 us; speedup vs baseline: 2.6638x; 1.3194x over previous
//
#include <hip/hip_runtime.h>

constexpr int N_U  = 100000;
constexpr int N_I  = 100000;
constexpr int NTOT = 200000;   // N_U + N_I
constexpr int D    = 64;
constexpr int Q    = 128;
constexpr int NNZ  = 3200000;
constexpr int SEG  = N_U * D;  // 6,400,000 floats per output segment

constexpr int G1_CHUNK = 400;
constexpr int G1_NBLK  = 250;  // ceil(100000/400)

// bucket sort params: bucket = row >> 9 (512 rows/bucket)
constexpr int BROWS   = 512;
constexpr int NBUCK   = (NTOT + BROWS - 1) / BROWS;  // 391
constexpr int P_CHUNK = 8192;                        // edges per P1/P3 block
constexpr int P_NBLK  = (NNZ + P_CHUNK - 1) / P_CHUNK;  // 391

// ---------------- P1: per-block bucket histogram (LDS only, no atomics) ----
__global__ void __launch_bounds__(512) k_bhist(const int* __restrict__ row,
                                               int* __restrict__ part) {
  __shared__ int h[NBUCK];
  const int t = threadIdx.x;
  if (t < NBUCK) h[t] = 0;
  __syncthreads();
  const int e0 = blockIdx.x * P_CHUNK;
#pragma unroll
  for (int i = 0; i < P_CHUNK / 512; ++i) {
    int e = e0 + i * 512 + t;
    if (e < NNZ) atomicAdd(&h[row[e] >> 9], 1);
  }
  __syncthreads();
  if (t < NBUCK) part[blockIdx.x * NBUCK + t] = h[t];
}

// ---------------- P2: column scan over blocks + bucket scan ----------------
// outb[blk][b] = # edges of bucket b in blocks < blk ; bbase[b] = bucket start
__global__ void __launch_bounds__(512) k_bscan(int* __restrict__ part,
                                               int* __restrict__ outb,
                                               int* __restrict__ bbase) {
  __shared__ int s[512];
  const int t = threadIdx.x;
  int run = 0;
  if (t < NBUCK) {
    for (int blk = 0; blk < P_NBLK; ++blk) {
      int v = part[blk * NBUCK + t];
      outb[blk * NBUCK + t] = run;
      run += v;
    }
  }
  const int own = (t < NBUCK) ? run : 0;
  s[t] = own;
  __syncthreads();
  for (int off = 1; off < 512; off <<= 1) {
    int y = (t >= off) ? s[t - off] : 0;
    __syncthreads();
    s[t] += y;
    __syncthreads();
  }
  int excl = s[t] - own;
  if (t <= NBUCK) bbase[t] = excl;  // bbase[NBUCK] == NNZ
}

// ---------------- P3: scatter edges to bucket-grouped ebuck ----------------
// ebuck[i] = (col | lrow<<18, val_bits)
__global__ void __launch_bounds__(512) k_mscat(const int* __restrict__ row,
                                               const int* __restrict__ col,
                                               const float* __restrict__ val,
                                               const int* __restrict__ outb,
                                               const int* __restrict__ bbase,
                                               int2* __restrict__ ebuck) {
  __shared__ int cur[NBUCK];
  const int t = threadIdx.x;
  if (t < NBUCK) cur[t] = bbase[t] + outb[blockIdx.x * NBUCK + t];
  __syncthreads();
  const int e0 = blockIdx.x * P_CHUNK;
#pragma unroll
  for (int i = 0; i < P_CHUNK / 512; ++i) {
    int e = e0 + i * 512 + t;
    if (e < NNZ) {
      int r = row[e];
      int b = r >> 9;
      int pos = atomicAdd(&cur[b], 1);
      ebuck[pos] = make_int2(col[e] | ((r & (BROWS - 1)) << 18), __float_as_int(val[e]));
    }
  }
}

// ---------------- P4: within-bucket row sort + rowptr emission -------------
__global__ void __launch_bounds__(512) k_rsort(const int* __restrict__ bbase,
                                               const int2* __restrict__ ebuck,
                                               int2* __restrict__ edges,
                                               int* __restrict__ rowptr) {
  __shared__ int s[512];
  __shared__ int cur[512];
  const int t = threadIdx.x;
  const int b = blockIdx.x;
  const int eb0 = bbase[b], eb1 = bbase[b + 1];
  // phase 1: row histogram
  cur[t] = 0;
  __syncthreads();
  for (int e = eb0 + t; e < eb1; e += 512) atomicAdd(&cur[ebuck[e].x >> 18], 1);
  __syncthreads();
  // phase 2: exclusive scan of 512 row counts
  const int own = cur[t];
  s[t] = own;
  __syncthreads();
  for (int off = 1; off < 512; off <<= 1) {
    int y = (t >= off) ? s[t - off] : 0;
    __syncthreads();
    s[t] += y;
    __syncthreads();
  }
  const int excl = s[t] - own;
  const int r = (b << 9) + t;
  if (r < NTOT) rowptr[r] = eb0 + excl;
  if (b == NBUCK - 1 && t == 0) rowptr[NTOT] = NNZ;
  cur[t] = eb0 + excl;
  __syncthreads();
  // phase 3: place edges at exact row positions (writes within 64KB -> L2)
  for (int e = eb0 + t; e < eb1; e += 512) {
    int2 kv = ebuck[e];
    int pos = atomicAdd(&cur[kv.x >> 18], 1);
    edges[pos] = make_int2(kv.x & 0x3FFFF, kv.y);
  }
}

// ---------------- SpMM (gather, wave per row, lane = d, 8-deep MLP) ---------
// xu: base for cols < N_U ; xim: base already offset so xim + (c<<6) is valid
// for cols >= N_U. For contiguous layer buffers pass xu == xim == buffer.
// MODE 0: y = sum, acc = sum           (layer 1, initializes acc)
// MODE 1: y = sum, acc += sum          (layer 2)
// MODE 2: no y,    acc = (acc+sum)/3   (layer 3, fused mean)
template <int MODE>
__global__ void k_spmm(const int* __restrict__ rowptr, const int2* __restrict__ edges,
                       const float* __restrict__ xu, const float* __restrict__ xim,
                       float* __restrict__ y,
                       float* __restrict__ accu, float* __restrict__ acci) {
  const int r = (blockIdx.x * 256 + threadIdx.x) >> 6;
  const int lane = threadIdx.x & 63;
  if (r >= NTOT) return;
  const int e0 = rowptr[r], e1 = rowptr[r + 1];
  float sum = 0.f;
  int e = e0;
#define SRC(dd) ((((dd).x < N_U) ? xu : xim) + ((size_t)(dd).x << 6) + lane)
  for (; e + 8 <= e1; e += 8) {
    int2 d0 = edges[e + 0], d1 = edges[e + 1], d2 = edges[e + 2], d3 = edges[e + 3];
    int2 d4 = edges[e + 4], d5 = edges[e + 5], d6 = edges[e + 6], d7 = edges[e + 7];
    float a0 = *SRC(d0);
    float a1 = *SRC(d1);
    float a2 = *SRC(d2);
    float a3 = *SRC(d3);
    float a4 = *SRC(d4);
    float a5 = *SRC(d5);
    float a6 = *SRC(d6);
    float a7 = *SRC(d7);
    sum = fmaf(__int_as_float(d0.y), a0, sum);
    sum = fmaf(__int_as_float(d1.y), a1, sum);
    sum = fmaf(__int_as_float(d2.y), a2, sum);
    sum = fmaf(__int_as_float(d3.y), a3, sum);
    sum = fmaf(__int_as_float(d4.y), a4, sum);
    sum = fmaf(__int_as_float(d5.y), a5, sum);
    sum = fmaf(__int_as_float(d6.y), a6, sum);
    sum = fmaf(__int_as_float(d7.y), a7, sum);
  }
  for (; e + 2 <= e1; e += 2) {
    int2 d0 = edges[e + 0], d1 = edges[e + 1];
    float a0 = *SRC(d0);
    float a1 = *SRC(d1);
    sum = fmaf(__int_as_float(d0.y), a0, sum);
    sum = fmaf(__int_as_float(d1.y), a1, sum);
  }
  if (e < e1) {
    int2 d0 = edges[e];
    sum = fmaf(__int_as_float(d0.y), *SRC(d0), sum);
  }
#undef SRC
  if (MODE != 2) y[(size_t)r * D + lane] = sum;
  float* acc = (r < N_U) ? (accu + (size_t)r * D + lane)
                         : (acci + (size_t)(r - N_U) * D + lane);
  if (MODE == 0)      *acc = sum;
  else if (MODE == 1) *acc += sum;
  else                *acc = (*acc + sum) * (1.f / 3.f);
}

// ---------------- G1: Ppart[mat][blk] = W(128 x nchunk) @ X(nchunk x 64) ----
__global__ void __launch_bounds__(512) k_g1(const float* __restrict__ ut,
                                            const float* __restrict__ vt,
                                            const float* __restrict__ accu,
                                            const float* __restrict__ acci,
                                            float* __restrict__ Ppart) {
  __shared__ float Wl[128 * 65];
  __shared__ float Xl[64 * 64];
  const int mat = blockIdx.y;
  const float* __restrict__ W = mat ? vt : ut;      // (Q, N_U) row-major
  const float* __restrict__ X = mat ? acci : accu;  // (N_U, 64) holds mean
  const int t = threadIdx.x;
  const int q0 = (t >> 4) * 4;   // 32 q-groups
  const int d0 = (t & 15) * 4;   // 16 d-groups
  const int n0 = blockIdx.x * G1_CHUNK;
  const int n1 = min(n0 + G1_CHUNK, N_U);
  float4 a0 = {0, 0, 0, 0}, a1 = {0, 0, 0, 0}, a2 = {0, 0, 0, 0}, a3 = {0, 0, 0, 0};
  for (int k = n0; k < n1; k += 64) {
#pragma unroll
    for (int rep = 0; rep < 2; ++rep) {
      int f4 = t + rep * 512;
      int row = f4 >> 4;
      int c4 = (f4 & 15) * 4;
      int gr = k + row;
      float4 v = (gr < n1) ? *reinterpret_cast<const float4*>(X + (size_t)gr * 64 + c4)
                           : float4{0, 0, 0, 0};
      *reinterpret_cast<float4*>(&Xl[row * 64 + c4]) = v;
    }
    {
      int q = t >> 2;
      int c16 = (t & 3) * 16;
#pragma unroll
      for (int jj = 0; jj < 4; ++jj) {
        int kk = c16 + jj * 4;
        int gk = k + kk;
        float4 v = (gk < n1) ? *reinterpret_cast<const float4*>(W + (size_t)q * N_U + gk)
                             : float4{0, 0, 0, 0};
        *reinterpret_cast<float4*>(&Wl[q * 65 + kk]) = v;
      }
    }
    __syncthreads();
#pragma unroll 2
    for (int kk = 0; kk < 64; kk += 4) {
      float4 w0 = *reinterpret_cast<const float4*>(&Wl[(q0 + 0) * 65 + kk]);
      float4 w1 = *reinterpret_cast<const float4*>(&Wl[(q0 + 1) * 65 + kk]);
      float4 w2 = *reinterpret_cast<const float4*>(&Wl[(q0 + 2) * 65 + kk]);
      float4 w3 = *reinterpret_cast<const float4*>(&Wl[(q0 + 3) * 65 + kk]);
      float4 x0 = *reinterpret_cast<const float4*>(&Xl[(kk + 0) * 64 + d0]);
      float4 x1 = *reinterpret_cast<const float4*>(&Xl[(kk + 1) * 64 + d0]);
      float4 x2 = *reinterpret_cast<const float4*>(&Xl[(kk + 2) * 64 + d0]);
      float4 x3 = *reinterpret_cast<const float4*>(&Xl[(kk + 3) * 64 + d0]);
#define FMA16(aj, wj)                                                                 \
  aj.x = fmaf(wj.x, x0.x, aj.x); aj.y = fmaf(wj.x, x0.y, aj.y);                       \
  aj.z = fmaf(wj.x, x0.z, aj.z); aj.w = fmaf(wj.x, x0.w, aj.w);                       \
  aj.x = fmaf(wj.y, x1.x, aj.x); aj.y = fmaf(wj.y, x1.y, aj.y);                       \
  aj.z = fmaf(wj.y, x1.z, aj.z); aj.w = fmaf(wj.y, x1.w, aj.w);                       \
  aj.x = fmaf(wj.z, x2.x, aj.x); aj.y = fmaf(wj.z, x2.y, aj.y);                       \
  aj.z = fmaf(wj.z, x2.z, aj.z); aj.w = fmaf(wj.z, x2.w, aj.w);                       \
  aj.x = fmaf(wj.w, x3.x, aj.x); aj.y = fmaf(wj.w, x3.y, aj.y);                       \
  aj.z = fmaf(wj.w, x3.z, aj.z); aj.w = fmaf(wj.w, x3.w, aj.w);
      FMA16(a0, w0)
      FMA16(a1, w1)
      FMA16(a2, w2)
      FMA16(a3, w3)
#undef FMA16
    }
    __syncthreads();
  }
  float* dst = Ppart + ((size_t)mat * G1_NBLK + blockIdx.x) * (Q * D);
  *reinterpret_cast<float4*>(dst + (q0 + 0) * 64 + d0) = a0;
  *reinterpret_cast<float4*>(dst + (q0 + 1) * 64 + d0) = a1;
  *reinterpret_cast<float4*>(dst + (q0 + 2) * 64 + d0) = a2;
  *reinterpret_cast<float4*>(dst + (q0 + 3) * 64 + d0) = a3;
}

// P[mat][q][d] = 3 * sum_blk Ppart[mat][blk][q][d]
__global__ void k_reduce(const float* __restrict__ Ppart, float* __restrict__ P) {
  int idx = blockIdx.x * 256 + threadIdx.x;  // 0..16383
  if (idx >= 2 * Q * D) return;
  int mat = idx >> 13;
  int qd = idx & (Q * D - 1);
  const float* src = Ppart + (size_t)mat * G1_NBLK * (Q * D) + qd;
  float s = 0.f;
#pragma unroll 4
  for (int b = 0; b < G1_NBLK; ++b) s += src[(size_t)b * (Q * D)];
  P[idx] = s * 3.f;
}

// ---------------- G2: svd_u = u_mul_s @ P_v ; svd_i = v_mul_s @ P_u ---------
__global__ void __launch_bounds__(256) k_g2(const float* __restrict__ u_mul_s,
                                            const float* __restrict__ v_mul_s,
                                            const float* __restrict__ P,
                                            float* __restrict__ svd_u,
                                            float* __restrict__ svd_i) {
  const int mat = blockIdx.y;
  const float* __restrict__ M  = mat ? v_mul_s : u_mul_s;  // (N_U, Q)
  const float* __restrict__ Pg = mat ? P : (P + Q * D);
  float* __restrict__ out      = mat ? svd_i : svd_u;
  const int d = threadIdx.x & 63;
  float4 p4[32];
#pragma unroll
  for (int q4 = 0; q4 < 32; ++q4)
    p4[q4] = make_float4(Pg[(4 * q4 + 0) * 64 + d], Pg[(4 * q4 + 1) * 64 + d],
                         Pg[(4 * q4 + 2) * 64 + d], Pg[(4 * q4 + 3) * 64 + d]);
  const int w = blockIdx.x * 4 + (threadIdx.x >> 6);
  const int nw = gridDim.x * 4;
  for (int r = w; r < N_U; r += nw) {
    const int ru = __builtin_amdgcn_readfirstlane(r);
    const float4* __restrict__ mrow =
        reinterpret_cast<const float4*>(M + (size_t)ru * Q);
    float s0 = 0.f, s1 = 0.f, s2 = 0.f, s3 = 0.f;
#pragma unroll
    for (int q4 = 0; q4 < 32; ++q4) {
      float4 m = mrow[q4];  // wave-uniform address -> scalar load
      s0 = fmaf(m.x, p4[q4].x, s0);
      s1 = fmaf(m.y, p4[q4].y, s1);
      s2 = fmaf(m.z, p4[q4].z, s2);
      s3 = fmaf(m.w, p4[q4].w, s3);
    }
    out[(size_t)ru * D + d] = (s0 + s1) + (s2 + s3);
  }
}

extern "C" void kernel_launch(void* const* d_in, const int* in_sizes, int n_in,
                              void* d_out, int out_size, void* d_ws, size_t ws_size,
                              hipStream_t stream) {
  const float* user_emb = (const float*)d_in[0];
  const float* item_emb = (const float*)d_in[1];
  const int*   adj_row  = (const int*)d_in[2];
  const int*   adj_col  = (const int*)d_in[3];
  const float* adj_vals = (const float*)d_in[4];
  const float* ut       = (const float*)d_in[5];
  const float* vt       = (const float*)d_in[6];
  const float* u_mul_s  = (const float*)d_in[7];
  const float* v_mul_s  = (const float*)d_in[8];
  float* out = (float*)d_out;

  char* ws = (char*)d_ws;
  size_t off = 0;
  auto alloc = [&](size_t bytes) -> void* {
    void* p = ws + off;
    off = (off + bytes + 255) & ~(size_t)255;
    return p;
  };
  float* xb     = (float*)alloc((size_t)NTOT * D * 4);            // 51.2 MB
  float* yb     = (float*)alloc((size_t)NTOT * D * 4);            // 51.2 MB
  int2*  ebuck  = (int2*)alloc((size_t)NNZ * 8);                  // 25.6 MB
  int2*  edges  = (int2*)alloc((size_t)NNZ * 8);                  // 25.6 MB
  int*   rowptr = (int*)alloc((size_t)(NTOT + 1) * 4);
  int*   part   = (int*)alloc((size_t)P_NBLK * NBUCK * 4);        // 611 KB
  int*   outb   = (int*)alloc((size_t)P_NBLK * NBUCK * 4);        // 611 KB
  int*   bbase  = (int*)alloc((size_t)(NBUCK + 1) * 4);
  float* P      = (float*)alloc(2 * Q * D * 4);                   // 64 KB
  float* Ppart  = (float*)alloc((size_t)2 * G1_NBLK * Q * D * 4); // 16.4 MB

  float* acc_u = out;                    // seg0 -> mean_u
  float* svd_u = out + (size_t)SEG;      // seg1
  float* acc_i = out + 2 * (size_t)SEG;  // seg2 -> mean_i
  float* svd_i = out + 3 * (size_t)SEG;  // seg3

  // CSR build: atomic-free multisplit (bucket = row>>9)
  k_bhist<<<P_NBLK, 512, 0, stream>>>(adj_row, part);
  k_bscan<<<1, 512, 0, stream>>>(part, outb, bbase);
  k_mscat<<<P_NBLK, 512, 0, stream>>>(adj_row, adj_col, adj_vals, outb, bbase, ebuck);
  k_rsort<<<NBUCK, 512, 0, stream>>>(bbase, ebuck, edges, rowptr);

  const int spmmGrid = (NTOT * 64) / 256;
  // layer 1: gather straight from the two input embedding arrays
  const float* item_off = (const float*)((const char*)item_emb - (size_t)SEG * 4);
  k_spmm<0><<<spmmGrid, 256, 0, stream>>>(rowptr, edges, user_emb, item_off, yb,
                                          acc_u, acc_i);
  // layer 2: yb -> xb (contiguous)
  k_spmm<1><<<spmmGrid, 256, 0, stream>>>(rowptr, edges, yb, yb, xb, acc_u, acc_i);
  // layer 3: xb -> (no y), fused mean
  k_spmm<2><<<spmmGrid, 256, 0, stream>>>(rowptr, edges, xb, xb, nullptr, acc_u, acc_i);

  // P_u partials (y=0, from mean_u/ut), P_v partials (y=1, from mean_i/vt)
  k_g1<<<dim3(G1_NBLK, 2), 512, 0, stream>>>(ut, vt, acc_u, acc_i, Ppart);
  k_reduce<<<(2 * Q * D + 255) / 256, 256, 0, stream>>>(Ppart, P);

  // y=0: svd_u = u_mul_s @ P_v ; y=1: svd_i = v_mul_s @ P_u
  k_g2<<<dim3(2048, 2), 256, 0, stream>>>(u_mul_s, v_mul_s, P, svd_u, svd_i);
}

// Round 6
// 763.011 us; speedup vs baseline: 2.7711x; 1.0403x over previous
//
#include <hip/hip_runtime.h>

constexpr int N_U  = 100000;
constexpr int N_I  = 100000;
constexpr int NTOT = 200000;   // N_U + N_I
constexpr int D    = 64;
constexpr int Q    = 128;
constexpr int NNZ  = 3200000;
constexpr int SEG  = N_U * D;  // 6,400,000 floats per output segment

constexpr int G1_CHUNK = 400;
constexpr int G1_NBLK  = 250;  // ceil(100000/400)

// bucket sort params: bucket = row >> 9 (512 rows/bucket)
constexpr int BROWS   = 512;
constexpr int NBUCK   = (NTOT + BROWS - 1) / BROWS;  // 391
constexpr int P_CHUNK = 8192;                        // edges per P1/P3 block
constexpr int P_NBLK  = (NNZ + P_CHUNK - 1) / P_CHUNK;  // 391

// G2 tiling
constexpr int G2_R    = 64;                              // rows per block
constexpr int G2_NBLK = (N_U + G2_R - 1) / G2_R;         // 1563
constexpr int MSTRIDE = 132;                             // M tile LDS stride (pad)

// ---------------- P1: per-block bucket histogram (LDS only) ----------------
__global__ void __launch_bounds__(512) k_bhist(const int* __restrict__ row,
                                               int* __restrict__ part) {
  __shared__ int h[NBUCK];
  const int t = threadIdx.x;
  if (t < NBUCK) h[t] = 0;
  __syncthreads();
  const int e0 = blockIdx.x * P_CHUNK;
#pragma unroll
  for (int i = 0; i < P_CHUNK / 512; ++i) {
    int e = e0 + i * 512 + t;
    if (e < NNZ) atomicAdd(&h[row[e] >> 9], 1);
  }
  __syncthreads();
  if (t < NBUCK) part[blockIdx.x * NBUCK + t] = h[t];
}

// ---------------- P2: column scan over blocks + bucket scan ----------------
__global__ void __launch_bounds__(512) k_bscan(int* __restrict__ part,
                                               int* __restrict__ outb,
                                               int* __restrict__ bbase) {
  __shared__ int s[512];
  const int t = threadIdx.x;
  int run = 0;
  if (t < NBUCK) {
    for (int blk = 0; blk < P_NBLK; ++blk) {
      int v = part[blk * NBUCK + t];
      outb[blk * NBUCK + t] = run;
      run += v;
    }
  }
  const int own = (t < NBUCK) ? run : 0;
  s[t] = own;
  __syncthreads();
  for (int off = 1; off < 512; off <<= 1) {
    int y = (t >= off) ? s[t - off] : 0;
    __syncthreads();
    s[t] += y;
    __syncthreads();
  }
  int excl = s[t] - own;
  if (t <= NBUCK) bbase[t] = excl;  // bbase[NBUCK] == NNZ
}

// ---------------- P3: scatter edges to bucket-grouped ebuck ----------------
__global__ void __launch_bounds__(512) k_mscat(const int* __restrict__ row,
                                               const int* __restrict__ col,
                                               const float* __restrict__ val,
                                               const int* __restrict__ outb,
                                               const int* __restrict__ bbase,
                                               int2* __restrict__ ebuck) {
  __shared__ int cur[NBUCK];
  const int t = threadIdx.x;
  if (t < NBUCK) cur[t] = bbase[t] + outb[blockIdx.x * NBUCK + t];
  __syncthreads();
  const int e0 = blockIdx.x * P_CHUNK;
#pragma unroll
  for (int i = 0; i < P_CHUNK / 512; ++i) {
    int e = e0 + i * 512 + t;
    if (e < NNZ) {
      int r = row[e];
      int b = r >> 9;
      int pos = atomicAdd(&cur[b], 1);
      ebuck[pos] = make_int2(col[e] | ((r & (BROWS - 1)) << 18), __float_as_int(val[e]));
    }
  }
}

// ---------------- P4: within-bucket row sort + rowptr emission -------------
__global__ void __launch_bounds__(512) k_rsort(const int* __restrict__ bbase,
                                               const int2* __restrict__ ebuck,
                                               int2* __restrict__ edges,
                                               int* __restrict__ rowptr) {
  __shared__ int s[512];
  __shared__ int cur[512];
  const int t = threadIdx.x;
  const int b = blockIdx.x;
  const int eb0 = bbase[b], eb1 = bbase[b + 1];
  cur[t] = 0;
  __syncthreads();
  for (int e = eb0 + t; e < eb1; e += 512) atomicAdd(&cur[ebuck[e].x >> 18], 1);
  __syncthreads();
  const int own = cur[t];
  s[t] = own;
  __syncthreads();
  for (int off = 1; off < 512; off <<= 1) {
    int y = (t >= off) ? s[t - off] : 0;
    __syncthreads();
    s[t] += y;
    __syncthreads();
  }
  const int excl = s[t] - own;
  const int r = (b << 9) + t;
  if (r < NTOT) rowptr[r] = eb0 + excl;
  if (b == NBUCK - 1 && t == 0) rowptr[NTOT] = NNZ;
  cur[t] = eb0 + excl;
  __syncthreads();
  for (int e = eb0 + t; e < eb1; e += 512) {
    int2 kv = ebuck[e];
    int pos = atomicAdd(&cur[kv.x >> 18], 1);
    edges[pos] = make_int2(kv.x & 0x3FFFF, kv.y);
  }
}

// ---------------- SpMM (gather, wave per row, lane = d, 8-deep MLP) ---------
template <int MODE>
__global__ void k_spmm(const int* __restrict__ rowptr, const int2* __restrict__ edges,
                       const float* __restrict__ xu, const float* __restrict__ xim,
                       float* __restrict__ y,
                       float* __restrict__ accu, float* __restrict__ acci) {
  const int r = (blockIdx.x * 256 + threadIdx.x) >> 6;
  const int lane = threadIdx.x & 63;
  if (r >= NTOT) return;
  const int e0 = rowptr[r], e1 = rowptr[r + 1];
  float sum = 0.f;
  int e = e0;
#define SRC(dd) ((((dd).x < N_U) ? xu : xim) + ((size_t)(dd).x << 6) + lane)
  for (; e + 8 <= e1; e += 8) {
    int2 d0 = edges[e + 0], d1 = edges[e + 1], d2 = edges[e + 2], d3 = edges[e + 3];
    int2 d4 = edges[e + 4], d5 = edges[e + 5], d6 = edges[e + 6], d7 = edges[e + 7];
    float a0 = *SRC(d0);
    float a1 = *SRC(d1);
    float a2 = *SRC(d2);
    float a3 = *SRC(d3);
    float a4 = *SRC(d4);
    float a5 = *SRC(d5);
    float a6 = *SRC(d6);
    float a7 = *SRC(d7);
    sum = fmaf(__int_as_float(d0.y), a0, sum);
    sum = fmaf(__int_as_float(d1.y), a1, sum);
    sum = fmaf(__int_as_float(d2.y), a2, sum);
    sum = fmaf(__int_as_float(d3.y), a3, sum);
    sum = fmaf(__int_as_float(d4.y), a4, sum);
    sum = fmaf(__int_as_float(d5.y), a5, sum);
    sum = fmaf(__int_as_float(d6.y), a6, sum);
    sum = fmaf(__int_as_float(d7.y), a7, sum);
  }
  for (; e + 2 <= e1; e += 2) {
    int2 d0 = edges[e + 0], d1 = edges[e + 1];
    float a0 = *SRC(d0);
    float a1 = *SRC(d1);
    sum = fmaf(__int_as_float(d0.y), a0, sum);
    sum = fmaf(__int_as_float(d1.y), a1, sum);
  }
  if (e < e1) {
    int2 d0 = edges[e];
    sum = fmaf(__int_as_float(d0.y), *SRC(d0), sum);
  }
#undef SRC
  if (MODE != 2) y[(size_t)r * D + lane] = sum;
  float* acc = (r < N_U) ? (accu + (size_t)r * D + lane)
                         : (acci + (size_t)(r - N_U) * D + lane);
  if (MODE == 0)      *acc = sum;
  else if (MODE == 1) *acc += sum;
  else                *acc = (*acc + sum) * (1.f / 3.f);
}

// ---------------- G1: Ppart[mat][blk] = W(128 x nchunk) @ X(nchunk x 64) ----
__global__ void __launch_bounds__(512) k_g1(const float* __restrict__ ut,
                                            const float* __restrict__ vt,
                                            const float* __restrict__ accu,
                                            const float* __restrict__ acci,
                                            float* __restrict__ Ppart) {
  __shared__ float Wl[128 * 65];
  __shared__ float Xl[64 * 64];
  const int mat = blockIdx.y;
  const float* __restrict__ W = mat ? vt : ut;      // (Q, N_U) row-major
  const float* __restrict__ X = mat ? acci : accu;  // (N_U, 64) holds mean
  const int t = threadIdx.x;
  const int q0 = (t >> 4) * 4;   // 32 q-groups
  const int d0 = (t & 15) * 4;   // 16 d-groups
  const int n0 = blockIdx.x * G1_CHUNK;
  const int n1 = min(n0 + G1_CHUNK, N_U);
  float4 a0 = {0, 0, 0, 0}, a1 = {0, 0, 0, 0}, a2 = {0, 0, 0, 0}, a3 = {0, 0, 0, 0};
  for (int k = n0; k < n1; k += 64) {
#pragma unroll
    for (int rep = 0; rep < 2; ++rep) {
      int f4 = t + rep * 512;
      int row = f4 >> 4;
      int c4 = (f4 & 15) * 4;
      int gr = k + row;
      float4 v = (gr < n1) ? *reinterpret_cast<const float4*>(X + (size_t)gr * 64 + c4)
                           : float4{0, 0, 0, 0};
      *reinterpret_cast<float4*>(&Xl[row * 64 + c4]) = v;
    }
    {
      int q = t >> 2;
      int c16 = (t & 3) * 16;
#pragma unroll
      for (int jj = 0; jj < 4; ++jj) {
        int kk = c16 + jj * 4;
        int gk = k + kk;
        float4 v = (gk < n1) ? *reinterpret_cast<const float4*>(W + (size_t)q * N_U + gk)
                             : float4{0, 0, 0, 0};
        *reinterpret_cast<float4*>(&Wl[q * 65 + kk]) = v;
      }
    }
    __syncthreads();
#pragma unroll 2
    for (int kk = 0; kk < 64; kk += 4) {
      float4 w0 = *reinterpret_cast<const float4*>(&Wl[(q0 + 0) * 65 + kk]);
      float4 w1 = *reinterpret_cast<const float4*>(&Wl[(q0 + 1) * 65 + kk]);
      float4 w2 = *reinterpret_cast<const float4*>(&Wl[(q0 + 2) * 65 + kk]);
      float4 w3 = *reinterpret_cast<const float4*>(&Wl[(q0 + 3) * 65 + kk]);
      float4 x0 = *reinterpret_cast<const float4*>(&Xl[(kk + 0) * 64 + d0]);
      float4 x1 = *reinterpret_cast<const float4*>(&Xl[(kk + 1) * 64 + d0]);
      float4 x2 = *reinterpret_cast<const float4*>(&Xl[(kk + 2) * 64 + d0]);
      float4 x3 = *reinterpret_cast<const float4*>(&Xl[(kk + 3) * 64 + d0]);
#define FMA16(aj, wj)                                                                 \
  aj.x = fmaf(wj.x, x0.x, aj.x); aj.y = fmaf(wj.x, x0.y, aj.y);                       \
  aj.z = fmaf(wj.x, x0.z, aj.z); aj.w = fmaf(wj.x, x0.w, aj.w);                       \
  aj.x = fmaf(wj.y, x1.x, aj.x); aj.y = fmaf(wj.y, x1.y, aj.y);                       \
  aj.z = fmaf(wj.y, x1.z, aj.z); aj.w = fmaf(wj.y, x1.w, aj.w);                       \
  aj.x = fmaf(wj.z, x2.x, aj.x); aj.y = fmaf(wj.z, x2.y, aj.y);                       \
  aj.z = fmaf(wj.z, x2.z, aj.z); aj.w = fmaf(wj.z, x2.w, aj.w);                       \
  aj.x = fmaf(wj.w, x3.x, aj.x); aj.y = fmaf(wj.w, x3.y, aj.y);                       \
  aj.z = fmaf(wj.w, x3.z, aj.z); aj.w = fmaf(wj.w, x3.w, aj.w);
      FMA16(a0, w0)
      FMA16(a1, w1)
      FMA16(a2, w2)
      FMA16(a3, w3)
#undef FMA16
    }
    __syncthreads();
  }
  float* dst = Ppart + ((size_t)mat * G1_NBLK + blockIdx.x) * (Q * D);
  *reinterpret_cast<float4*>(dst + (q0 + 0) * 64 + d0) = a0;
  *reinterpret_cast<float4*>(dst + (q0 + 1) * 64 + d0) = a1;
  *reinterpret_cast<float4*>(dst + (q0 + 2) * 64 + d0) = a2;
  *reinterpret_cast<float4*>(dst + (q0 + 3) * 64 + d0) = a3;
}

// P[mat][q][d] = 3 * sum_blk Ppart[mat][blk][q][d]
__global__ void k_reduce(const float* __restrict__ Ppart, float* __restrict__ P) {
  int idx = blockIdx.x * 256 + threadIdx.x;  // 0..16383
  if (idx >= 2 * Q * D) return;
  int mat = idx >> 13;
  int qd = idx & (Q * D - 1);
  const float* src = Ppart + (size_t)mat * G1_NBLK * (Q * D) + qd;
  float s = 0.f;
#pragma unroll 4
  for (int b = 0; b < G1_NBLK; ++b) s += src[(size_t)b * (Q * D)];
  P[idx] = s * 3.f;
}

// ---------------- G2: LDS-tiled GEMM, out(N x 64) = M(N x 128) @ P(128 x 64)
// Block: 256 threads, 64 rows x 64 cols. Full P in LDS (32 KB); M tile
// 64 x 128 (stride 132 pad -> 2-way bank pattern, free). Thread = 4r x 4c.
__global__ void __launch_bounds__(256) k_g2(const float* __restrict__ u_mul_s,
                                            const float* __restrict__ v_mul_s,
                                            const float* __restrict__ P,
                                            float* __restrict__ svd_u,
                                            float* __restrict__ svd_i) {
  __shared__ float Pl[Q * D];            // 32 KB, [k][c] stride 64
  __shared__ float Ml[G2_R * MSTRIDE];   // 33.8 KB, [row][k] stride 132
  const int mat = blockIdx.y;
  const float* __restrict__ M  = mat ? v_mul_s : u_mul_s;  // (N_U, 128)
  const float* __restrict__ Pg = mat ? P : (P + Q * D);
  float* __restrict__ outp     = mat ? svd_i : svd_u;
  const int t = threadIdx.x;
  const int r0 = blockIdx.x * G2_R;
  // stage P (2048 float4, 8 per thread, coalesced; layout matches row-major)
#pragma unroll
  for (int i = 0; i < 8; ++i) {
    int idx = i * 256 + t;
    reinterpret_cast<float4*>(Pl)[idx] = reinterpret_cast<const float4*>(Pg)[idx];
  }
  // stage M tile: 64 rows x 128 floats, coalesced float4
#pragma unroll
  for (int pass = 0; pass < 8; ++pass) {
    int row = pass * 8 + (t >> 5);       // 0..63
    int c4 = (t & 31) * 4;               // 0..124
    int gr = r0 + row;
    float4 v = (gr < N_U) ? *reinterpret_cast<const float4*>(M + (size_t)gr * Q + c4)
                          : float4{0, 0, 0, 0};
    *reinterpret_cast<float4*>(&Ml[row * MSTRIDE + c4]) = v;
  }
  __syncthreads();
  const int rb = (t >> 4) * 4;           // local row base (0..60)
  const int c0 = (t & 15) * 4;           // col base (0..60)
  float4 a0 = {0, 0, 0, 0}, a1 = {0, 0, 0, 0}, a2 = {0, 0, 0, 0}, a3 = {0, 0, 0, 0};
#pragma unroll 8
  for (int kk = 0; kk < Q; kk += 4) {
    float4 m0 = *reinterpret_cast<const float4*>(&Ml[(rb + 0) * MSTRIDE + kk]);
    float4 m1 = *reinterpret_cast<const float4*>(&Ml[(rb + 1) * MSTRIDE + kk]);
    float4 m2 = *reinterpret_cast<const float4*>(&Ml[(rb + 2) * MSTRIDE + kk]);
    float4 m3 = *reinterpret_cast<const float4*>(&Ml[(rb + 3) * MSTRIDE + kk]);
    float4 p0 = *reinterpret_cast<const float4*>(&Pl[(kk + 0) * D + c0]);
    float4 p1 = *reinterpret_cast<const float4*>(&Pl[(kk + 1) * D + c0]);
    float4 p2 = *reinterpret_cast<const float4*>(&Pl[(kk + 2) * D + c0]);
    float4 p3 = *reinterpret_cast<const float4*>(&Pl[(kk + 3) * D + c0]);
#define G2FMA(aj, mj)                                                                 \
  aj.x = fmaf(mj.x, p0.x, aj.x); aj.y = fmaf(mj.x, p0.y, aj.y);                       \
  aj.z = fmaf(mj.x, p0.z, aj.z); aj.w = fmaf(mj.x, p0.w, aj.w);                       \
  aj.x = fmaf(mj.y, p1.x, aj.x); aj.y = fmaf(mj.y, p1.y, aj.y);                       \
  aj.z = fmaf(mj.y, p1.z, aj.z); aj.w = fmaf(mj.y, p1.w, aj.w);                       \
  aj.x = fmaf(mj.z, p2.x, aj.x); aj.y = fmaf(mj.z, p2.y, aj.y);                       \
  aj.z = fmaf(mj.z, p2.z, aj.z); aj.w = fmaf(mj.z, p2.w, aj.w);                       \
  aj.x = fmaf(mj.w, p3.x, aj.x); aj.y = fmaf(mj.w, p3.y, aj.y);                       \
  aj.z = fmaf(mj.w, p3.z, aj.z); aj.w = fmaf(mj.w, p3.w, aj.w);
    G2FMA(a0, m0)
    G2FMA(a1, m1)
    G2FMA(a2, m2)
    G2FMA(a3, m3)
#undef G2FMA
  }
  const int gr = r0 + rb;
  if (gr + 0 < N_U) *reinterpret_cast<float4*>(outp + (size_t)(gr + 0) * D + c0) = a0;
  if (gr + 1 < N_U) *reinterpret_cast<float4*>(outp + (size_t)(gr + 1) * D + c0) = a1;
  if (gr + 2 < N_U) *reinterpret_cast<float4*>(outp + (size_t)(gr + 2) * D + c0) = a2;
  if (gr + 3 < N_U) *reinterpret_cast<float4*>(outp + (size_t)(gr + 3) * D + c0) = a3;
}

extern "C" void kernel_launch(void* const* d_in, const int* in_sizes, int n_in,
                              void* d_out, int out_size, void* d_ws, size_t ws_size,
                              hipStream_t stream) {
  const float* user_emb = (const float*)d_in[0];
  const float* item_emb = (const float*)d_in[1];
  const int*   adj_row  = (const int*)d_in[2];
  const int*   adj_col  = (const int*)d_in[3];
  const float* adj_vals = (const float*)d_in[4];
  const float* ut       = (const float*)d_in[5];
  const float* vt       = (const float*)d_in[6];
  const float* u_mul_s  = (const float*)d_in[7];
  const float* v_mul_s  = (const float*)d_in[8];
  float* out = (float*)d_out;

  char* ws = (char*)d_ws;
  size_t off = 0;
  auto alloc = [&](size_t bytes) -> void* {
    void* p = ws + off;
    off = (off + bytes + 255) & ~(size_t)255;
    return p;
  };
  float* xb     = (float*)alloc((size_t)NTOT * D * 4);            // 51.2 MB
  float* yb     = (float*)alloc((size_t)NTOT * D * 4);            // 51.2 MB
  int2*  ebuck  = (int2*)alloc((size_t)NNZ * 8);                  // 25.6 MB
  int2*  edges  = (int2*)alloc((size_t)NNZ * 8);                  // 25.6 MB
  int*   rowptr = (int*)alloc((size_t)(NTOT + 1) * 4);
  int*   part   = (int*)alloc((size_t)P_NBLK * NBUCK * 4);        // 611 KB
  int*   outb   = (int*)alloc((size_t)P_NBLK * NBUCK * 4);        // 611 KB
  int*   bbase  = (int*)alloc((size_t)(NBUCK + 1) * 4);
  float* P      = (float*)alloc(2 * Q * D * 4);                   // 64 KB
  float* Ppart  = (float*)alloc((size_t)2 * G1_NBLK * Q * D * 4); // 16.4 MB

  float* acc_u = out;                    // seg0 -> mean_u
  float* svd_u = out + (size_t)SEG;      // seg1
  float* acc_i = out + 2 * (size_t)SEG;  // seg2 -> mean_i
  float* svd_i = out + 3 * (size_t)SEG;  // seg3

  // CSR build: atomic-free multisplit (bucket = row>>9)
  k_bhist<<<P_NBLK, 512, 0, stream>>>(adj_row, part);
  k_bscan<<<1, 512, 0, stream>>>(part, outb, bbase);
  k_mscat<<<P_NBLK, 512, 0, stream>>>(adj_row, adj_col, adj_vals, outb, bbase, ebuck);
  k_rsort<<<NBUCK, 512, 0, stream>>>(bbase, ebuck, edges, rowptr);

  const int spmmGrid = (NTOT * 64) / 256;
  // layer 1: gather straight from the two input embedding arrays
  const float* item_off = (const float*)((const char*)item_emb - (size_t)SEG * 4);
  k_spmm<0><<<spmmGrid, 256, 0, stream>>>(rowptr, edges, user_emb, item_off, yb,
                                          acc_u, acc_i);
  // layer 2: yb -> xb (contiguous)
  k_spmm<1><<<spmmGrid, 256, 0, stream>>>(rowptr, edges, yb, yb, xb, acc_u, acc_i);
  // layer 3: xb -> (no y), fused mean
  k_spmm<2><<<spmmGrid, 256, 0, stream>>>(rowptr, edges, xb, xb, nullptr, acc_u, acc_i);

  // P_u partials (y=0, from mean_u/ut), P_v partials (y=1, from mean_i/vt)
  k_g1<<<dim3(G1_NBLK, 2), 512, 0, stream>>>(ut, vt, acc_u, acc_i, Ppart);
  k_reduce<<<(2 * Q * D + 255) / 256, 256, 0, stream>>>(Ppart, P);

  // y=0: svd_u = u_mul_s @ P_v ; y=1: svd_i = v_mul_s @ P_u
  k_g2<<<dim3(G2_NBLK, 2), 256, 0, stream>>>(u_mul_s, v_mul_s, P, svd_u, svd_i);
}

// Round 7
// 703.314 us; speedup vs baseline: 3.0063x; 1.0849x over previous
//
#include <hip/hip_runtime.h>

constexpr int N_U  = 100000;
constexpr int N_I  = 100000;
constexpr int NTOT = 200000;   // N_U + N_I
constexpr int D    = 64;
constexpr int Q    = 128;
constexpr int NNZ  = 3200000;
constexpr int SEG  = N_U * D;  // 6,400,000 floats per output segment

constexpr int G1_CHUNK = 400;
constexpr int G1_NBLK  = 250;  // ceil(100000/400)

// bucket sort params: bucket = row >> 9 (512 rows/bucket)
constexpr int BROWS   = 512;
constexpr int NBUCK   = (NTOT + BROWS - 1) / BROWS;  // 391
constexpr int P_CHUNK = 8192;                        // edges per P1/P3 block
constexpr int P_NBLK  = (NNZ + P_CHUNK - 1) / P_CHUNK;  // 391

// G2 tiling
constexpr int G2_R    = 64;                              // rows per block
constexpr int G2_NBLK = (N_U + G2_R - 1) / G2_R;         // 1563
constexpr int MSTRIDE = 132;                             // M tile LDS stride (pad)

// bf16 helpers (RNE pack, shift unpack)
__device__ __forceinline__ unsigned short f2bf(float f) {
  unsigned int b = __float_as_uint(f);
  return (unsigned short)((b + 0x7fff + ((b >> 16) & 1)) >> 16);
}
__device__ __forceinline__ float bf2f(unsigned short u) {
  return __uint_as_float((unsigned int)u << 16);
}

// ---------------- P1: per-block bucket histogram (LDS only) ----------------
__global__ void __launch_bounds__(512) k_bhist(const int* __restrict__ row,
                                               int* __restrict__ part) {
  __shared__ int h[NBUCK];
  const int t = threadIdx.x;
  if (t < NBUCK) h[t] = 0;
  __syncthreads();
  const int e0 = blockIdx.x * P_CHUNK;
#pragma unroll
  for (int i = 0; i < P_CHUNK / 512; ++i) {
    int e = e0 + i * 512 + t;
    if (e < NNZ) atomicAdd(&h[row[e] >> 9], 1);
  }
  __syncthreads();
  if (t < NBUCK) part[blockIdx.x * NBUCK + t] = h[t];
}

// ---------------- P2: column scan over blocks + bucket scan ----------------
__global__ void __launch_bounds__(512) k_bscan(int* __restrict__ part,
                                               int* __restrict__ outb,
                                               int* __restrict__ bbase) {
  __shared__ int s[512];
  const int t = threadIdx.x;
  int run = 0;
  if (t < NBUCK) {
    for (int blk = 0; blk < P_NBLK; ++blk) {
      int v = part[blk * NBUCK + t];
      outb[blk * NBUCK + t] = run;
      run += v;
    }
  }
  const int own = (t < NBUCK) ? run : 0;
  s[t] = own;
  __syncthreads();
  for (int off = 1; off < 512; off <<= 1) {
    int y = (t >= off) ? s[t - off] : 0;
    __syncthreads();
    s[t] += y;
    __syncthreads();
  }
  int excl = s[t] - own;
  if (t <= NBUCK) bbase[t] = excl;  // bbase[NBUCK] == NNZ
}

// ---------------- P3: scatter edges to bucket-grouped ebuck ----------------
__global__ void __launch_bounds__(512) k_mscat(const int* __restrict__ row,
                                               const int* __restrict__ col,
                                               const float* __restrict__ val,
                                               const int* __restrict__ outb,
                                               const int* __restrict__ bbase,
                                               int2* __restrict__ ebuck) {
  __shared__ int cur[NBUCK];
  const int t = threadIdx.x;
  if (t < NBUCK) cur[t] = bbase[t] + outb[blockIdx.x * NBUCK + t];
  __syncthreads();
  const int e0 = blockIdx.x * P_CHUNK;
#pragma unroll
  for (int i = 0; i < P_CHUNK / 512; ++i) {
    int e = e0 + i * 512 + t;
    if (e < NNZ) {
      int r = row[e];
      int b = r >> 9;
      int pos = atomicAdd(&cur[b], 1);
      ebuck[pos] = make_int2(col[e] | ((r & (BROWS - 1)) << 18), __float_as_int(val[e]));
    }
  }
}

// ---------------- P4: within-bucket row sort + rowptr emission -------------
__global__ void __launch_bounds__(512) k_rsort(const int* __restrict__ bbase,
                                               const int2* __restrict__ ebuck,
                                               int2* __restrict__ edges,
                                               int* __restrict__ rowptr) {
  __shared__ int s[512];
  __shared__ int cur[512];
  const int t = threadIdx.x;
  const int b = blockIdx.x;
  const int eb0 = bbase[b], eb1 = bbase[b + 1];
  cur[t] = 0;
  __syncthreads();
  for (int e = eb0 + t; e < eb1; e += 512) atomicAdd(&cur[ebuck[e].x >> 18], 1);
  __syncthreads();
  const int own = cur[t];
  s[t] = own;
  __syncthreads();
  for (int off = 1; off < 512; off <<= 1) {
    int y = (t >= off) ? s[t - off] : 0;
    __syncthreads();
    s[t] += y;
    __syncthreads();
  }
  const int excl = s[t] - own;
  const int r = (b << 9) + t;
  if (r < NTOT) rowptr[r] = eb0 + excl;
  if (b == NBUCK - 1 && t == 0) rowptr[NTOT] = NNZ;
  cur[t] = eb0 + excl;
  __syncthreads();
  for (int e = eb0 + t; e < eb1; e += 512) {
    int2 kv = ebuck[e];
    int pos = atomicAdd(&cur[kv.x >> 18], 1);
    edges[pos] = make_int2(kv.x & 0x3FFFF, kv.y);
  }
}

// ---------------- cvt: concat inputs -> bf16 ego buffer --------------------
__global__ void k_cvt(const float* __restrict__ user_emb,
                      const float* __restrict__ item_emb,
                      unsigned short* __restrict__ e0) {
  int i = blockIdx.x * 256 + threadIdx.x;  // 8 elems per thread
  if (i >= NTOT * D / 8) return;
  size_t base = (size_t)i * 8;
  const float* src = (base < (size_t)SEG) ? (user_emb + base) : (item_emb + base - SEG);
  float4 v0 = *reinterpret_cast<const float4*>(src);
  float4 v1 = *reinterpret_cast<const float4*>(src + 4);
  union { unsigned short us[8]; uint4 u4; } pk;
  pk.us[0] = f2bf(v0.x); pk.us[1] = f2bf(v0.y); pk.us[2] = f2bf(v0.z); pk.us[3] = f2bf(v0.w);
  pk.us[4] = f2bf(v1.x); pk.us[5] = f2bf(v1.y); pk.us[6] = f2bf(v1.z); pk.us[7] = f2bf(v1.w);
  *reinterpret_cast<uint4*>(e0 + base) = pk.u4;
}

// ---------------- SpMM bf16 (gather, wave per row, lane = d, 8-deep MLP) ----
__global__ void k_spmm(const int* __restrict__ rowptr, const int2* __restrict__ edges,
                       const unsigned short* __restrict__ src,
                       unsigned short* __restrict__ dst) {
  const int r = (blockIdx.x * 256 + threadIdx.x) >> 6;
  const int lane = threadIdx.x & 63;
  if (r >= NTOT) return;
  const int e0 = rowptr[r], e1 = rowptr[r + 1];
  float sum = 0.f;
  int e = e0;
  for (; e + 8 <= e1; e += 8) {
    int2 d0 = edges[e + 0], d1 = edges[e + 1], d2 = edges[e + 2], d3 = edges[e + 3];
    int2 d4 = edges[e + 4], d5 = edges[e + 5], d6 = edges[e + 6], d7 = edges[e + 7];
    unsigned short u0 = src[((size_t)d0.x << 6) + lane];
    unsigned short u1 = src[((size_t)d1.x << 6) + lane];
    unsigned short u2 = src[((size_t)d2.x << 6) + lane];
    unsigned short u3 = src[((size_t)d3.x << 6) + lane];
    unsigned short u4 = src[((size_t)d4.x << 6) + lane];
    unsigned short u5 = src[((size_t)d5.x << 6) + lane];
    unsigned short u6 = src[((size_t)d6.x << 6) + lane];
    unsigned short u7 = src[((size_t)d7.x << 6) + lane];
    sum = fmaf(__int_as_float(d0.y), bf2f(u0), sum);
    sum = fmaf(__int_as_float(d1.y), bf2f(u1), sum);
    sum = fmaf(__int_as_float(d2.y), bf2f(u2), sum);
    sum = fmaf(__int_as_float(d3.y), bf2f(u3), sum);
    sum = fmaf(__int_as_float(d4.y), bf2f(u4), sum);
    sum = fmaf(__int_as_float(d5.y), bf2f(u5), sum);
    sum = fmaf(__int_as_float(d6.y), bf2f(u6), sum);
    sum = fmaf(__int_as_float(d7.y), bf2f(u7), sum);
  }
  for (; e + 2 <= e1; e += 2) {
    int2 d0 = edges[e + 0], d1 = edges[e + 1];
    unsigned short u0 = src[((size_t)d0.x << 6) + lane];
    unsigned short u1 = src[((size_t)d1.x << 6) + lane];
    sum = fmaf(__int_as_float(d0.y), bf2f(u0), sum);
    sum = fmaf(__int_as_float(d1.y), bf2f(u1), sum);
  }
  if (e < e1) {
    int2 d0 = edges[e];
    sum = fmaf(__int_as_float(d0.y), bf2f(src[((size_t)d0.x << 6) + lane]), sum);
  }
  dst[((size_t)r << 6) + lane] = f2bf(sum);
}

// ---------------- mean: (e1+e2+e3)/3 -> f32 out segments -------------------
__global__ void k_mean(const unsigned short* __restrict__ e1,
                       const unsigned short* __restrict__ e2,
                       const unsigned short* __restrict__ e3,
                       float* __restrict__ mean_u, float* __restrict__ mean_i) {
  int i = blockIdx.x * 256 + threadIdx.x;  // 8 elems per thread
  if (i >= NTOT * D / 8) return;
  size_t base = (size_t)i * 8;
  uint4 a = *reinterpret_cast<const uint4*>(e1 + base);
  uint4 b = *reinterpret_cast<const uint4*>(e2 + base);
  uint4 c = *reinterpret_cast<const uint4*>(e3 + base);
  union { uint4 u4; unsigned short us[8]; } ua, ub, uc;
  ua.u4 = a; ub.u4 = b; uc.u4 = c;
  float o[8];
#pragma unroll
  for (int j = 0; j < 8; ++j)
    o[j] = (bf2f(ua.us[j]) + bf2f(ub.us[j]) + bf2f(uc.us[j])) * (1.f / 3.f);
  float* dstp = (base < (size_t)SEG) ? (mean_u + base) : (mean_i + base - SEG);
  *reinterpret_cast<float4*>(dstp) = make_float4(o[0], o[1], o[2], o[3]);
  *reinterpret_cast<float4*>(dstp + 4) = make_float4(o[4], o[5], o[6], o[7]);
}

// ---------------- G1: Ppart[mat][blk] = W(128 x nchunk) @ X(nchunk x 64) ----
__global__ void __launch_bounds__(512) k_g1(const float* __restrict__ ut,
                                            const float* __restrict__ vt,
                                            const float* __restrict__ accu,
                                            const float* __restrict__ acci,
                                            float* __restrict__ Ppart) {
  __shared__ float Wl[128 * 65];
  __shared__ float Xl[64 * 64];
  const int mat = blockIdx.y;
  const float* __restrict__ W = mat ? vt : ut;      // (Q, N_U) row-major
  const float* __restrict__ X = mat ? acci : accu;  // (N_U, 64) holds mean
  const int t = threadIdx.x;
  const int q0 = (t >> 4) * 4;   // 32 q-groups
  const int d0 = (t & 15) * 4;   // 16 d-groups
  const int n0 = blockIdx.x * G1_CHUNK;
  const int n1 = min(n0 + G1_CHUNK, N_U);
  float4 a0 = {0, 0, 0, 0}, a1 = {0, 0, 0, 0}, a2 = {0, 0, 0, 0}, a3 = {0, 0, 0, 0};
  for (int k = n0; k < n1; k += 64) {
#pragma unroll
    for (int rep = 0; rep < 2; ++rep) {
      int f4 = t + rep * 512;
      int row = f4 >> 4;
      int c4 = (f4 & 15) * 4;
      int gr = k + row;
      float4 v = (gr < n1) ? *reinterpret_cast<const float4*>(X + (size_t)gr * 64 + c4)
                           : float4{0, 0, 0, 0};
      *reinterpret_cast<float4*>(&Xl[row * 64 + c4]) = v;
    }
    {
      int q = t >> 2;
      int c16 = (t & 3) * 16;
#pragma unroll
      for (int jj = 0; jj < 4; ++jj) {
        int kk = c16 + jj * 4;
        int gk = k + kk;
        float4 v = (gk < n1) ? *reinterpret_cast<const float4*>(W + (size_t)q * N_U + gk)
                             : float4{0, 0, 0, 0};
        *reinterpret_cast<float4*>(&Wl[q * 65 + kk]) = v;
      }
    }
    __syncthreads();
#pragma unroll 2
    for (int kk = 0; kk < 64; kk += 4) {
      float4 w0 = *reinterpret_cast<const float4*>(&Wl[(q0 + 0) * 65 + kk]);
      float4 w1 = *reinterpret_cast<const float4*>(&Wl[(q0 + 1) * 65 + kk]);
      float4 w2 = *reinterpret_cast<const float4*>(&Wl[(q0 + 2) * 65 + kk]);
      float4 w3 = *reinterpret_cast<const float4*>(&Wl[(q0 + 3) * 65 + kk]);
      float4 x0 = *reinterpret_cast<const float4*>(&Xl[(kk + 0) * 64 + d0]);
      float4 x1 = *reinterpret_cast<const float4*>(&Xl[(kk + 1) * 64 + d0]);
      float4 x2 = *reinterpret_cast<const float4*>(&Xl[(kk + 2) * 64 + d0]);
      float4 x3 = *reinterpret_cast<const float4*>(&Xl[(kk + 3) * 64 + d0]);
#define FMA16(aj, wj)                                                                 \
  aj.x = fmaf(wj.x, x0.x, aj.x); aj.y = fmaf(wj.x, x0.y, aj.y);                       \
  aj.z = fmaf(wj.x, x0.z, aj.z); aj.w = fmaf(wj.x, x0.w, aj.w);                       \
  aj.x = fmaf(wj.y, x1.x, aj.x); aj.y = fmaf(wj.y, x1.y, aj.y);                       \
  aj.z = fmaf(wj.y, x1.z, aj.z); aj.w = fmaf(wj.y, x1.w, aj.w);                       \
  aj.x = fmaf(wj.z, x2.x, aj.x); aj.y = fmaf(wj.z, x2.y, aj.y);                       \
  aj.z = fmaf(wj.z, x2.z, aj.z); aj.w = fmaf(wj.z, x2.w, aj.w);                       \
  aj.x = fmaf(wj.w, x3.x, aj.x); aj.y = fmaf(wj.w, x3.y, aj.y);                       \
  aj.z = fmaf(wj.w, x3.z, aj.z); aj.w = fmaf(wj.w, x3.w, aj.w);
      FMA16(a0, w0)
      FMA16(a1, w1)
      FMA16(a2, w2)
      FMA16(a3, w3)
#undef FMA16
    }
    __syncthreads();
  }
  float* dst = Ppart + ((size_t)mat * G1_NBLK + blockIdx.x) * (Q * D);
  *reinterpret_cast<float4*>(dst + (q0 + 0) * 64 + d0) = a0;
  *reinterpret_cast<float4*>(dst + (q0 + 1) * 64 + d0) = a1;
  *reinterpret_cast<float4*>(dst + (q0 + 2) * 64 + d0) = a2;
  *reinterpret_cast<float4*>(dst + (q0 + 3) * 64 + d0) = a3;
}

// P[mat][q][d] = 3 * sum_blk Ppart[mat][blk][q][d]
__global__ void k_reduce(const float* __restrict__ Ppart, float* __restrict__ P) {
  int idx = blockIdx.x * 256 + threadIdx.x;  // 0..16383
  if (idx >= 2 * Q * D) return;
  int mat = idx >> 13;
  int qd = idx & (Q * D - 1);
  const float* src = Ppart + (size_t)mat * G1_NBLK * (Q * D) + qd;
  float s = 0.f;
#pragma unroll 4
  for (int b = 0; b < G1_NBLK; ++b) s += src[(size_t)b * (Q * D)];
  P[idx] = s * 3.f;
}

// ---------------- G2: LDS-tiled GEMM, out(N x 64) = M(N x 128) @ P(128 x 64)
__global__ void __launch_bounds__(256) k_g2(const float* __restrict__ u_mul_s,
                                            const float* __restrict__ v_mul_s,
                                            const float* __restrict__ P,
                                            float* __restrict__ svd_u,
                                            float* __restrict__ svd_i) {
  __shared__ float Pl[Q * D];            // 32 KB, [k][c] stride 64
  __shared__ float Ml[G2_R * MSTRIDE];   // 33.8 KB, [row][k] stride 132
  const int mat = blockIdx.y;
  const float* __restrict__ M  = mat ? v_mul_s : u_mul_s;  // (N_U, 128)
  const float* __restrict__ Pg = mat ? P : (P + Q * D);
  float* __restrict__ outp     = mat ? svd_i : svd_u;
  const int t = threadIdx.x;
  const int r0 = blockIdx.x * G2_R;
#pragma unroll
  for (int i = 0; i < 8; ++i) {
    int idx = i * 256 + t;
    reinterpret_cast<float4*>(Pl)[idx] = reinterpret_cast<const float4*>(Pg)[idx];
  }
#pragma unroll
  for (int pass = 0; pass < 8; ++pass) {
    int row = pass * 8 + (t >> 5);       // 0..63
    int c4 = (t & 31) * 4;               // 0..124
    int gr = r0 + row;
    float4 v = (gr < N_U) ? *reinterpret_cast<const float4*>(M + (size_t)gr * Q + c4)
                          : float4{0, 0, 0, 0};
    *reinterpret_cast<float4*>(&Ml[row * MSTRIDE + c4]) = v;
  }
  __syncthreads();
  const int rb = (t >> 4) * 4;           // local row base (0..60)
  const int c0 = (t & 15) * 4;           // col base (0..60)
  float4 a0 = {0, 0, 0, 0}, a1 = {0, 0, 0, 0}, a2 = {0, 0, 0, 0}, a3 = {0, 0, 0, 0};
#pragma unroll 8
  for (int kk = 0; kk < Q; kk += 4) {
    float4 m0 = *reinterpret_cast<const float4*>(&Ml[(rb + 0) * MSTRIDE + kk]);
    float4 m1 = *reinterpret_cast<const float4*>(&Ml[(rb + 1) * MSTRIDE + kk]);
    float4 m2 = *reinterpret_cast<const float4*>(&Ml[(rb + 2) * MSTRIDE + kk]);
    float4 m3 = *reinterpret_cast<const float4*>(&Ml[(rb + 3) * MSTRIDE + kk]);
    float4 p0 = *reinterpret_cast<const float4*>(&Pl[(kk + 0) * D + c0]);
    float4 p1 = *reinterpret_cast<const float4*>(&Pl[(kk + 1) * D + c0]);
    float4 p2 = *reinterpret_cast<const float4*>(&Pl[(kk + 2) * D + c0]);
    float4 p3 = *reinterpret_cast<const float4*>(&Pl[(kk + 3) * D + c0]);
#define G2FMA(aj, mj)                                                                 \
  aj.x = fmaf(mj.x, p0.x, aj.x); aj.y = fmaf(mj.x, p0.y, aj.y);                       \
  aj.z = fmaf(mj.x, p0.z, aj.z); aj.w = fmaf(mj.x, p0.w, aj.w);                       \
  aj.x = fmaf(mj.y, p1.x, aj.x); aj.y = fmaf(mj.y, p1.y, aj.y);                       \
  aj.z = fmaf(mj.y, p1.z, aj.z); aj.w = fmaf(mj.y, p1.w, aj.w);                       \
  aj.x = fmaf(mj.z, p2.x, aj.x); aj.y = fmaf(mj.z, p2.y, aj.y);                       \
  aj.z = fmaf(mj.z, p2.z, aj.z); aj.w = fmaf(mj.z, p2.w, aj.w);                       \
  aj.x = fmaf(mj.w, p3.x, aj.x); aj.y = fmaf(mj.w, p3.y, aj.y);                       \
  aj.z = fmaf(mj.w, p3.z, aj.z); aj.w = fmaf(mj.w, p3.w, aj.w);
    G2FMA(a0, m0)
    G2FMA(a1, m1)
    G2FMA(a2, m2)
    G2FMA(a3, m3)
#undef G2FMA
  }
  const int gr = r0 + rb;
  if (gr + 0 < N_U) *reinterpret_cast<float4*>(outp + (size_t)(gr + 0) * D + c0) = a0;
  if (gr + 1 < N_U) *reinterpret_cast<float4*>(outp + (size_t)(gr + 1) * D + c0) = a1;
  if (gr + 2 < N_U) *reinterpret_cast<float4*>(outp + (size_t)(gr + 2) * D + c0) = a2;
  if (gr + 3 < N_U) *reinterpret_cast<float4*>(outp + (size_t)(gr + 3) * D + c0) = a3;
}

extern "C" void kernel_launch(void* const* d_in, const int* in_sizes, int n_in,
                              void* d_out, int out_size, void* d_ws, size_t ws_size,
                              hipStream_t stream) {
  const float* user_emb = (const float*)d_in[0];
  const float* item_emb = (const float*)d_in[1];
  const int*   adj_row  = (const int*)d_in[2];
  const int*   adj_col  = (const int*)d_in[3];
  const float* adj_vals = (const float*)d_in[4];
  const float* ut       = (const float*)d_in[5];
  const float* vt       = (const float*)d_in[6];
  const float* u_mul_s  = (const float*)d_in[7];
  const float* v_mul_s  = (const float*)d_in[8];
  float* out = (float*)d_out;

  char* ws = (char*)d_ws;
  size_t off = 0;
  auto alloc = [&](size_t bytes) -> void* {
    void* p = ws + off;
    off = (off + bytes + 255) & ~(size_t)255;
    return p;
  };
  unsigned short* eb0 = (unsigned short*)alloc((size_t)NTOT * D * 2);  // 25.6 MB
  unsigned short* eb1 = (unsigned short*)alloc((size_t)NTOT * D * 2);
  unsigned short* eb2 = (unsigned short*)alloc((size_t)NTOT * D * 2);
  unsigned short* eb3 = (unsigned short*)alloc((size_t)NTOT * D * 2);
  int2*  ebuck  = (int2*)alloc((size_t)NNZ * 8);                  // 25.6 MB
  int2*  edges  = (int2*)alloc((size_t)NNZ * 8);                  // 25.6 MB
  int*   rowptr = (int*)alloc((size_t)(NTOT + 1) * 4);
  int*   part   = (int*)alloc((size_t)P_NBLK * NBUCK * 4);        // 611 KB
  int*   outb   = (int*)alloc((size_t)P_NBLK * NBUCK * 4);        // 611 KB
  int*   bbase  = (int*)alloc((size_t)(NBUCK + 1) * 4);
  float* P      = (float*)alloc(2 * Q * D * 4);                   // 64 KB
  float* Ppart  = (float*)alloc((size_t)2 * G1_NBLK * Q * D * 4); // 16.4 MB

  float* mean_u = out;                   // seg0
  float* svd_u  = out + (size_t)SEG;     // seg1
  float* mean_i = out + 2 * (size_t)SEG; // seg2
  float* svd_i  = out + 3 * (size_t)SEG; // seg3

  // CSR build: atomic-free multisplit (bucket = row>>9)
  k_bhist<<<P_NBLK, 512, 0, stream>>>(adj_row, part);
  k_bscan<<<1, 512, 0, stream>>>(part, outb, bbase);
  k_mscat<<<P_NBLK, 512, 0, stream>>>(adj_row, adj_col, adj_vals, outb, bbase, ebuck);
  k_rsort<<<NBUCK, 512, 0, stream>>>(bbase, ebuck, edges, rowptr);

  // inputs -> bf16 concat ego
  k_cvt<<<(NTOT * D / 8 + 255) / 256, 256, 0, stream>>>(user_emb, item_emb, eb0);

  const int spmmGrid = (NTOT * 64) / 256;
  k_spmm<<<spmmGrid, 256, 0, stream>>>(rowptr, edges, eb0, eb1);
  k_spmm<<<spmmGrid, 256, 0, stream>>>(rowptr, edges, eb1, eb2);
  k_spmm<<<spmmGrid, 256, 0, stream>>>(rowptr, edges, eb2, eb3);

  // mean = (e1+e2+e3)/3 -> f32 segments
  k_mean<<<(NTOT * D / 8 + 255) / 256, 256, 0, stream>>>(eb1, eb2, eb3, mean_u, mean_i);

  // P_u partials (y=0, from mean_u/ut), P_v partials (y=1, from mean_i/vt)
  k_g1<<<dim3(G1_NBLK, 2), 512, 0, stream>>>(ut, vt, mean_u, mean_i, Ppart);
  k_reduce<<<(2 * Q * D + 255) / 256, 256, 0, stream>>>(Ppart, P);

  // y=0: svd_u = u_mul_s @ P_v ; y=1: svd_i = v_mul_s @ P_u
  k_g2<<<dim3(G2_NBLK, 2), 256, 0, stream>>>(u_mul_s, v_mul_s, P, svd_u, svd_i);
}